// Round 3
// baseline (503.588 us; speedup 1.0000x reference)
//
#include <hip/hip_runtime.h>
#include <stdint.h>

#define QN    300
#define WN    10
#define CD    640
#define IJ    196
#define MROWS 1960              // WN*IJ
#define NTOT  58800             // QN*IJ
#define OUTQ  384160            // MROWS*IJ
#define EPSV  1e-8f

#define NT_TILES 460            // n tiles of 128
#define MT_TILES 16             // m tiles of 128
#define NWG      (NT_TILES*MT_TILES)   // 7360, divisible by 8
#define CPX      (NWG/8)        // 920

typedef __attribute__((ext_vector_type(8))) short bf16x8;
typedef __attribute__((ext_vector_type(4))) float f32x4;

__device__ __forceinline__ unsigned short f2bf(float f) {
    uint32_t u = __float_as_uint(f);
    u += 0x7FFFu + ((u >> 16) & 1u);   // RNE
    return (unsigned short)(u >> 16);
}

__device__ __forceinline__ void gload16(const void* g, void* l) {
    __builtin_amdgcn_global_load_lds(
        (const __attribute__((address_space(1))) void*)g,
        (__attribute__((address_space(3))) void*)l,
        16, 0, 0);
}

// ---------------------------------------------------------------------------
// Pre-pass: X[B][640][196] fp32 -> XT[B*196][640] bf16 (k contiguous), with
// the full 3-bit st-swizzle baked per 16B unit WITHIN each 8-unit (64-elem)
// K-group: stored_unit = (u&8) | ((u&7) ^ (row&7)).  Also fp32 norms.
// ---------------------------------------------------------------------------
__global__ __launch_bounds__(256)
void prep_kernel(const float* __restrict__ X, uint4* __restrict__ XT,
                 float* __restrict__ nrm)
{
    __shared__ float T[128][21];
    __shared__ float ssL[16][17];

    const int b  = blockIdx.y;
    const int i0 = blockIdx.x * 16;
    const int t  = threadIdx.x;
    const float* Xb = X + (size_t)b * (CD * IJ);

    // phase-1: thread reads float4 along i for one c-row
    const int cA  = t >> 2;              // 0..63
    const int i4  = (t & 3) * 4;         // 0,4,8,12
    const int iv  = i0 + i4;
    const bool liv = (iv <= IJ - 4);

    // phase-2: thread owns (i_local, 8-c unit)
    const int il = t >> 4;               // 0..15
    const int u  = t & 15;               // 0..15
    float ss = 0.f;

    const int ig   = i0 + il;
    const bool wok = (ig < IJ);
    const int rowg = b * IJ + (wok ? ig : IJ - 1);
    const int uxor = rowg & 7;           // 3-bit swizzle key

    for (int cc = 0; cc < CD / 128; ++cc) {
        #pragma unroll
        for (int pass = 0; pass < 2; ++pass) {
            int cl = pass * 64 + cA;
            int c  = cc * 128 + cl;
            float4 v = make_float4(0.f, 0.f, 0.f, 0.f);
            if (liv) v = *(const float4*)&Xb[(size_t)c * IJ + iv];
            T[cl][i4 + 0] = v.x; T[cl][i4 + 1] = v.y;
            T[cl][i4 + 2] = v.z; T[cl][i4 + 3] = v.w;
        }
        __syncthreads();
        float v[8];
        #pragma unroll
        for (int r = 0; r < 8; ++r) { v[r] = T[u * 8 + r][il]; ss += v[r] * v[r]; }
        if (wok) {
            union { unsigned short s[8]; uint4 q; } pk;
            #pragma unroll
            for (int r = 0; r < 8; ++r) pk.s[r] = f2bf(v[r]);
            int us = (u & 8) | ((u & 7) ^ uxor);
            XT[(size_t)rowg * (CD / 8) + cc * 16 + us] = pk.q;
        }
        __syncthreads();
    }

    ssL[il][u] = ss;
    __syncthreads();
    if (t < 16) {
        int igw = i0 + t;
        if (igw < IJ) {
            float s = 0.f;
            #pragma unroll
            for (int k = 0; k < 16; ++k) s += ssL[t][k];
            nrm[b * IJ + igw] = sqrtf(s);
        }
    }
}

// ---------------------------------------------------------------------------
// GEMM: C[m][n] = sum_c AT[m][c]*BT[n][c].  128x128 tile, BK=64, 4 waves,
// 4x4 acc of 16x16x32.  global_load_lds from pre-swizzled bf16; ds_read with
// matching 3-bit XOR -> conflict-free.  1-D grid + bijective XCD chunk
// swizzle, m-tile fast within a chunk (B-panel L2 reuse).
// ---------------------------------------------------------------------------
__global__ __launch_bounds__(256)
void gemm_kernel(const uint4* __restrict__ AT, const uint4* __restrict__ BT,
                 const float* __restrict__ pn, const float* __restrict__ qn,
                 float* __restrict__ out)
{
    __shared__ unsigned short As[128 * 64];
    __shared__ unsigned short Bs[128 * 64];

    const int bid = blockIdx.x;
    const int swz = (bid & 7) * CPX + (bid >> 3);   // bijective (7360%8==0)
    const int mt  = swz & (MT_TILES - 1);
    const int nt  = swz >> 4;
    const int m0  = mt * 128;
    const int n0  = nt * 128;

    const int t  = threadIdx.x;
    const int w  = t >> 6, l = t & 63;
    const int fr = l & 15, fq = l >> 4;
    const int wm0 = (w >> 1) * 64, wn0 = (w & 1) * 64;

    // staging: round r covers rows [r*32 + w*8, +8); lane: row += l>>3, unit l&7
    const int srow  = w * 8 + (l >> 3);
    const int sunit = l & 7;

    f32x4 acc[4][4];
    #pragma unroll
    for (int a = 0; a < 4; ++a)
        #pragma unroll
        for (int bb = 0; bb < 4; ++bb)
            acc[a][bb] = (f32x4){0.f, 0.f, 0.f, 0.f};

    for (int kk = 0; kk < CD / 64; ++kk) {
        #pragma unroll
        for (int r = 0; r < 4; ++r) {
            int ra = m0 + r * 32 + srow; if (ra > MROWS - 1) ra = MROWS - 1;
            gload16(AT + (size_t)ra * 80 + kk * 8 + sunit,
                    (char*)As + (r * 32 + w * 8) * 128);
            int rb = n0 + r * 32 + srow; if (rb > NTOT - 1) rb = NTOT - 1;
            gload16(BT + (size_t)rb * 80 + kk * 8 + sunit,
                    (char*)Bs + (r * 32 + w * 8) * 128);
        }
        __syncthreads();
        #pragma unroll
        for (int ks = 0; ks < 2; ++ks) {
            bf16x8 af[4], bfv[4];
            #pragma unroll
            for (int tm = 0; tm < 4; ++tm) {
                int row  = wm0 + tm * 16 + fr;
                int unit = (fq + ks * 4) ^ (row & 7);
                af[tm] = *(const bf16x8*)&As[row * 64 + unit * 8];
            }
            #pragma unroll
            for (int tn = 0; tn < 4; ++tn) {
                int row  = wn0 + tn * 16 + fr;
                int unit = (fq + ks * 4) ^ (row & 7);
                bfv[tn] = *(const bf16x8*)&Bs[row * 64 + unit * 8];
            }
            #pragma unroll
            for (int tm = 0; tm < 4; ++tm)
                #pragma unroll
                for (int tn = 0; tn < 4; ++tn)
                    acc[tm][tn] = __builtin_amdgcn_mfma_f32_16x16x32_bf16(
                        af[tm], bfv[tn], acc[tm][tn], 0, 0, 0);
        }
        __syncthreads();
    }

    // epilogue: out[q*OUTQ + m*196 + j] = acc / max(rp*rq, eps)
    float  rqv[4];
    int    nvalid[4];
    size_t obase[4];
    #pragma unroll
    for (int tn = 0; tn < 4; ++tn) {
        int n = n0 + wn0 + tn * 16 + fr;
        nvalid[tn] = (n < NTOT);
        int nc = nvalid[tn] ? n : NTOT - 1;
        int q  = nc / IJ;
        int j  = nc - q * IJ;
        rqv[tn]   = qn[nc];
        obase[tn] = (size_t)q * OUTQ + j;
    }
    #pragma unroll
    for (int tm = 0; tm < 4; ++tm) {
        #pragma unroll
        for (int rr = 0; rr < 4; ++rr) {
            int m = m0 + wm0 + tm * 16 + fq * 4 + rr;
            if (m < MROWS) {
                float rp = pn[m];
                #pragma unroll
                for (int tn = 0; tn < 4; ++tn) {
                    if (nvalid[tn]) {
                        float d = fmaxf(rp * rqv[tn], EPSV);
                        out[obase[tn] + (size_t)m * IJ] =
                            acc[tm][tn][rr] * __builtin_amdgcn_rcpf(d);
                    }
                }
            }
        }
    }
}

// ---------------------------------------------------------------------------
// Fallback (round-1 kernel, known-passing) if ws_size is insufficient.
// ---------------------------------------------------------------------------
#define BMF 128
#define BNF 224
#define LPAD 40
__global__ __launch_bounds__(512, 4)
void sim_fallback(const float* __restrict__ proto,
                  const float* __restrict__ query,
                  float* __restrict__ out)
{
    __shared__ unsigned short As[BMF][LPAD];
    __shared__ unsigned short Bs[BNF][LPAD];
    __shared__ float redA[4][BMF];
    __shared__ float redB[2][BNF];
    __shared__ float rpS[BMF];
    __shared__ float rqS[BNF];

    const int tid = threadIdx.x;
    const int m0  = blockIdx.x * BMF;
    const int q   = blockIdx.y;

    const int mA  = tid & (BMF - 1);
    const int krA = tid >> 7;
    const int wiA = m0 + mA;
    const bool va = (wiA < MROWS);
    const int wA  = va ? (wiA / IJ) : 0;
    const int iA  = va ? (wiA - wA * IJ) : 0;
    const float* pA = proto + wA * (CD * IJ) + iA;

    const bool tb  = (tid < 448);
    const int jB   = tb ? (tid % BNF) : 0;
    const int krB  = tb ? (tid / BNF) : 0;
    const bool vb  = tb && (jB < IJ);
    const float* qB = query + q * (CD * IJ) + jB;

    float ssA = 0.f, ssB = 0.f;

    const int wv   = tid >> 6;
    const int lane = tid & 63;
    const int wm0  = (wv >> 1) * 32;
    const int wn0  = (wv & 1) * 112;
    const int fr   = lane & 15;
    const int fq   = lane >> 4;

    f32x4 acc[2][7];
    #pragma unroll
    for (int a = 0; a < 2; a++)
        #pragma unroll
        for (int b = 0; b < 7; b++)
            acc[a][b] = (f32x4){0.f, 0.f, 0.f, 0.f};

    for (int it = 0; it < CD / 32; ++it) {
        const int c0 = it * 32;
        {
            float v[8];
            #pragma unroll
            for (int e = 0; e < 8; e++) {
                int c = c0 + krA * 8 + e;
                v[e] = va ? pA[c * IJ] : 0.f;
            }
            #pragma unroll
            for (int e = 0; e < 8; e++) ssA += v[e] * v[e];
            union { unsigned short s[8]; uint4 u; } pk;
            #pragma unroll
            for (int e = 0; e < 8; e++) pk.s[e] = f2bf(v[e]);
            *(uint4*)&As[mA][krA * 8] = pk.u;
        }
        if (tb) {
            #pragma unroll
            for (int h = 0; h < 2; ++h) {
                float v[8];
                #pragma unroll
                for (int e = 0; e < 8; e++) {
                    int c = c0 + krB * 16 + h * 8 + e;
                    v[e] = vb ? qB[c * IJ] : 0.f;
                }
                #pragma unroll
                for (int e = 0; e < 8; e++) ssB += v[e] * v[e];
                union { unsigned short s[8]; uint4 u; } pk;
                #pragma unroll
                for (int e = 0; e < 8; e++) pk.s[e] = f2bf(v[e]);
                *(uint4*)&Bs[jB][krB * 16 + h * 8] = pk.u;
            }
        }
        __syncthreads();
        bf16x8 af[2], bfv[7];
        #pragma unroll
        for (int tm = 0; tm < 2; tm++)
            af[tm] = *(const bf16x8*)&As[wm0 + tm * 16 + fr][fq * 8];
        #pragma unroll
        for (int tn = 0; tn < 7; tn++)
            bfv[tn] = *(const bf16x8*)&Bs[wn0 + tn * 16 + fr][fq * 8];
        #pragma unroll
        for (int tm = 0; tm < 2; tm++)
            #pragma unroll
            for (int tn = 0; tn < 7; tn++)
                acc[tm][tn] = __builtin_amdgcn_mfma_f32_16x16x32_bf16(
                    af[tm], bfv[tn], acc[tm][tn], 0, 0, 0);
        __syncthreads();
    }

    redA[krA][mA] = ssA;
    if (tb) redB[krB][jB] = ssB;
    __syncthreads();
    if (tid < BMF) {
        rpS[tid] = sqrtf(redA[0][tid] + redA[1][tid] + redA[2][tid] + redA[3][tid]);
    } else if (tid >= 256 && tid < 256 + BNF) {
        int j = tid - 256;
        rqS[j] = sqrtf(redB[0][j] + redB[1][j]);
    }
    __syncthreads();

    #pragma unroll
    for (int tm = 0; tm < 2; tm++) {
        #pragma unroll
        for (int tn = 0; tn < 7; tn++) {
            #pragma unroll
            for (int r = 0; r < 4; r++) {
                int rl = wm0 + tm * 16 + fq * 4 + r;
                int cl = wn0 + tn * 16 + fr;
                int wi = m0 + rl;
                if (wi < MROWS && cl < IJ) {
                    float denom = fmaxf(rpS[rl] * rqS[cl], 1e-8f);
                    out[(size_t)(q * MROWS + wi) * IJ + cl] = acc[tm][tn][r] / denom;
                }
            }
        }
    }
}

// ---------------------------------------------------------------------------
extern "C" void kernel_launch(void* const* d_in, const int* in_sizes, int n_in,
                              void* d_out, int out_size, void* d_ws, size_t ws_size,
                              hipStream_t stream) {
    const float* proto = (const float*)d_in[0];
    const float* query = (const float*)d_in[1];
    float* out = (float*)d_out;

    // workspace layout
    const size_t off_pT = 0;                       // 1960*640*2 = 2,508,800
    const size_t off_qT = 2508800;                 // 58800*640*2 = 75,264,000
    const size_t off_pn = 77772800;                // 1960*4
    const size_t off_qn = 77780736;                // 58800*4
    const size_t need   = 78015936;

    if (ws_size < need) {
        dim3 grid((MROWS + BMF - 1) / BMF, QN);
        sim_fallback<<<grid, 512, 0, stream>>>(proto, query, out);
        return;
    }

    char* ws = (char*)d_ws;
    uint4* pT = (uint4*)(ws + off_pT);
    uint4* qT = (uint4*)(ws + off_qT);
    float* pn = (float*)(ws + off_pn);
    float* qn = (float*)(ws + off_qn);

    prep_kernel<<<dim3(13, QN), 256, 0, stream>>>(query, qT, qn);
    prep_kernel<<<dim3(13, WN), 256, 0, stream>>>(proto, pT, pn);

    gemm_kernel<<<dim3(NWG), 256, 0, stream>>>(pT, qT, pn, qn, out);
}

// Round 4
// 433.206 us; speedup vs baseline: 1.1625x; 1.1625x over previous
//
#include <hip/hip_runtime.h>
#include <stdint.h>

#define QN    300
#define WN    10
#define CD    640
#define IJ    196
#define MROWS 1960              // WN*IJ
#define NTOT  58800             // QN*IJ
#define OUTQ  384160            // MROWS*IJ
#define EPSV  1e-8f

#define BM    128
#define BN    256
#define BK    64
#define BUFE  ((BM + BN) * BK)        // 24576 ushorts = 48 KB per buffer
#define NTK   (CD / BK)               // 10 K-tiles

#define MT_TILES 16                    // m tiles of 128 (pad 2048)
#define NT_TILES 230                   // n tiles of 256 (pad 58880)
#define NWG      (MT_TILES * NT_TILES) // 3680, divisible by 8
#define CPX      (NWG / 8)             // 460

typedef __attribute__((ext_vector_type(8))) short bf16x8;
typedef __attribute__((ext_vector_type(4))) float f32x4;

__device__ __forceinline__ unsigned short f2bf(float f) {
    uint32_t u = __float_as_uint(f);
    u += 0x7FFFu + ((u >> 16) & 1u);   // RNE
    return (unsigned short)(u >> 16);
}

__device__ __forceinline__ void gload16(const void* g, void* l) {
    __builtin_amdgcn_global_load_lds(
        (const __attribute__((address_space(1))) void*)g,
        (__attribute__((address_space(3))) void*)l,
        16, 0, 0);
}

// ---------------------------------------------------------------------------
// Pre-pass: X[B][640][196] fp32 -> XT[B*196][640] bf16 (k contiguous), with
// the 3-bit swizzle baked per 16B unit within each 8-unit (64-elem) K-group:
// stored_unit = (u&8) | ((u&7) ^ (row&7)).  Also fp32 norms.
// ---------------------------------------------------------------------------
__global__ __launch_bounds__(256)
void prep_kernel(const float* __restrict__ X, uint4* __restrict__ XT,
                 float* __restrict__ nrm)
{
    __shared__ float T[128][21];
    __shared__ float ssL[16][17];

    const int b  = blockIdx.y;
    const int i0 = blockIdx.x * 16;
    const int t  = threadIdx.x;
    const float* Xb = X + (size_t)b * (CD * IJ);

    const int cA  = t >> 2;              // 0..63
    const int i4  = (t & 3) * 4;         // 0,4,8,12
    const int iv  = i0 + i4;
    const bool liv = (iv <= IJ - 4);

    const int il = t >> 4;               // 0..15
    const int u  = t & 15;               // 0..15
    float ss = 0.f;

    const int ig   = i0 + il;
    const bool wok = (ig < IJ);
    const int rowg = b * IJ + (wok ? ig : IJ - 1);
    const int uxor = rowg & 7;

    for (int cc = 0; cc < CD / 128; ++cc) {
        #pragma unroll
        for (int pass = 0; pass < 2; ++pass) {
            int cl = pass * 64 + cA;
            int c  = cc * 128 + cl;
            float4 v = make_float4(0.f, 0.f, 0.f, 0.f);
            if (liv) v = *(const float4*)&Xb[(size_t)c * IJ + iv];
            T[cl][i4 + 0] = v.x; T[cl][i4 + 1] = v.y;
            T[cl][i4 + 2] = v.z; T[cl][i4 + 3] = v.w;
        }
        __syncthreads();
        float v[8];
        #pragma unroll
        for (int r = 0; r < 8; ++r) { v[r] = T[u * 8 + r][il]; ss += v[r] * v[r]; }
        if (wok) {
            union { unsigned short s[8]; uint4 q; } pk;
            #pragma unroll
            for (int r = 0; r < 8; ++r) pk.s[r] = f2bf(v[r]);
            int us = (u & 8) | ((u & 7) ^ uxor);
            XT[(size_t)rowg * (CD / 8) + cc * 16 + us] = pk.q;
        }
        __syncthreads();
    }

    ssL[il][u] = ss;
    __syncthreads();
    if (t < 16) {
        int igw = i0 + t;
        if (igw < IJ) {
            float s = 0.f;
            #pragma unroll
            for (int k = 0; k < 16; ++k) s += ssL[t][k];
            nrm[b * IJ + igw] = sqrtf(s);
        }
    }
}

// ---------------------------------------------------------------------------
// GEMM: C[m][n] = sum_c AT[m][c]*BT[n][c].  128x256 tile, BK=64, 8 waves
// (2M x 4N), 4x4 frags of 16x16x32.  3-deep circular LDS pipeline with
// counted vmcnt (T3+T4): tile t's loads get ~2 compute iterations to land;
// vmcnt never drains to 0 in the main loop.  Raw s_barrier (no __syncthreads
// -> no forced vmcnt(0) drain).  Pre-swizzled global source + XOR ds_read
// (conflict-free), bijective XCD chunk swizzle m-fast (B-panel L2 reuse).
// ---------------------------------------------------------------------------
__global__ __launch_bounds__(512, 2)
void gemm_kernel(const uint4* __restrict__ AT, const uint4* __restrict__ BT,
                 const float* __restrict__ pn, const float* __restrict__ qn,
                 float* __restrict__ out)
{
    __shared__ unsigned short lds[3 * BUFE];   // 144 KB

    const int bid = blockIdx.x;
    const int swz = (bid & 7) * CPX + (bid >> 3);   // bijective (3680%8==0)
    const int mt  = swz & (MT_TILES - 1);
    const int nt  = swz >> 4;
    const int m0  = mt * BM;
    const int n0  = nt * BN;

    const int t  = threadIdx.x;
    const int w  = t >> 6, l = t & 63;
    const int fr = l & 15, fq = l >> 4;
    const int wm0 = (w >> 2) * 64;   // 2 M-waves
    const int wn0 = (w & 3) * 64;    // 4 N-waves

    // ---- staging pointers (loop-invariant; advance by 8 uint4 per tile)
    const int lr = l >> 3, lu = l & 7;
    int ra0 = m0 +   0 + w * 8 + lr; if (ra0 > MROWS - 1) ra0 = MROWS - 1;
    int ra1 = m0 +  64 + w * 8 + lr; if (ra1 > MROWS - 1) ra1 = MROWS - 1;
    int rb0 = n0 +   0 + w * 8 + lr; if (rb0 > NTOT - 1) rb0 = NTOT - 1;
    int rb1 = n0 +  64 + w * 8 + lr; if (rb1 > NTOT - 1) rb1 = NTOT - 1;
    int rb2 = n0 + 128 + w * 8 + lr; if (rb2 > NTOT - 1) rb2 = NTOT - 1;
    int rb3 = n0 + 192 + w * 8 + lr; if (rb3 > NTOT - 1) rb3 = NTOT - 1;
    const uint4* ga0 = AT + (size_t)ra0 * 80 + lu;
    const uint4* ga1 = AT + (size_t)ra1 * 80 + lu;
    const uint4* gb0 = BT + (size_t)rb0 * 80 + lu;
    const uint4* gb1 = BT + (size_t)rb1 * 80 + lu;
    const uint4* gb2 = BT + (size_t)rb2 * 80 + lu;
    const uint4* gb3 = BT + (size_t)rb3 * 80 + lu;
    // wave-uniform LDS element offsets (HW adds lane*16B)
    const int la0 = (  0 + w * 8) * 64;
    const int la1 = ( 64 + w * 8) * 64;
    const int lb0 = BM * 64 + (  0 + w * 8) * 64;
    const int lb1 = BM * 64 + ( 64 + w * 8) * 64;
    const int lb2 = BM * 64 + (128 + w * 8) * 64;
    const int lb3 = BM * 64 + (192 + w * 8) * 64;

    // ---- fragment read bases + swizzle keys (loop-invariant)
    int baA[4], kyA[4], baB[4], kyB[4];
    #pragma unroll
    for (int i = 0; i < 4; ++i) {
        int rowa = wm0 + i * 16 + fr;
        baA[i] = rowa * 64;           kyA[i] = rowa & 7;
        int rowb = wn0 + i * 16 + fr;
        baB[i] = BM * 64 + rowb * 64; kyB[i] = rowb & 7;
    }

    f32x4 acc[4][4];
    #pragma unroll
    for (int a = 0; a < 4; ++a)
        #pragma unroll
        for (int bb = 0; bb < 4; ++bb)
            acc[a][bb] = (f32x4){0.f, 0.f, 0.f, 0.f};

#define STAGE(OFF)                                                        \
    gload16(ga0, (char*)&lds[(OFF) + la0]); ga0 += 8;                     \
    gload16(ga1, (char*)&lds[(OFF) + la1]); ga1 += 8;                     \
    gload16(gb0, (char*)&lds[(OFF) + lb0]); gb0 += 8;                     \
    gload16(gb1, (char*)&lds[(OFF) + lb1]); gb1 += 8;                     \
    gload16(gb2, (char*)&lds[(OFF) + lb2]); gb2 += 8;                     \
    gload16(gb3, (char*)&lds[(OFF) + lb3]); gb3 += 8;

#define COMPUTE(OFF)                                                      \
    _Pragma("unroll")                                                     \
    for (int ks = 0; ks < 2; ++ks) {                                      \
        bf16x8 af[4], bfv[4];                                             \
        _Pragma("unroll")                                                 \
        for (int i = 0; i < 4; ++i)                                       \
            af[i]  = *(const bf16x8*)&lds[(OFF) + baA[i] +                \
                                          (((fq + ks * 4) ^ kyA[i]) << 3)]; \
        _Pragma("unroll")                                                 \
        for (int i = 0; i < 4; ++i)                                       \
            bfv[i] = *(const bf16x8*)&lds[(OFF) + baB[i] +                \
                                          (((fq + ks * 4) ^ kyB[i]) << 3)]; \
        _Pragma("unroll")                                                 \
        for (int tm = 0; tm < 4; ++tm)                                    \
            _Pragma("unroll")                                             \
            for (int tn = 0; tn < 4; ++tn)                                \
                acc[tm][tn] = __builtin_amdgcn_mfma_f32_16x16x32_bf16(    \
                    af[tm], bfv[tn], acc[tm][tn], 0, 0, 0);               \
    }

    // ---- prologue: stage tiles 0 and 1 (12 loads in flight)
    STAGE(0);
    STAGE(BUFE);

    int oc = 0, os = 2 * BUFE;
    // ---- steady state: stage t+2, wait tile t (12 newer loads in flight)
    for (int tt = 0; tt < NTK - 2; ++tt) {
        STAGE(os);
        os = (os == 2 * BUFE) ? 0 : os + BUFE;
        asm volatile("s_waitcnt vmcnt(12)\n\ts_barrier" ::: "memory");
        __builtin_amdgcn_s_setprio(1);
        COMPUTE(oc);
        __builtin_amdgcn_s_setprio(0);
        asm volatile("s_barrier" ::: "memory");
        oc = (oc == 2 * BUFE) ? 0 : oc + BUFE;
    }
    // ---- tail: tile 8 (6 loads of tile 9 still in flight), then tile 9
    asm volatile("s_waitcnt vmcnt(6)\n\ts_barrier" ::: "memory");
    __builtin_amdgcn_s_setprio(1);
    COMPUTE(oc);
    __builtin_amdgcn_s_setprio(0);
    asm volatile("s_barrier" ::: "memory");
    oc = (oc == 2 * BUFE) ? 0 : oc + BUFE;
    asm volatile("s_waitcnt vmcnt(0)\n\ts_barrier" ::: "memory");
    __builtin_amdgcn_s_setprio(1);
    COMPUTE(oc);
    __builtin_amdgcn_s_setprio(0);

#undef STAGE
#undef COMPUTE

    // ---- epilogue: out[q*OUTQ + m*196 + j] = acc / max(rp*rq, eps)
    float  rqv[4];
    int    nvalid[4];
    size_t obase[4];
    #pragma unroll
    for (int tn = 0; tn < 4; ++tn) {
        int n = n0 + wn0 + tn * 16 + fr;
        nvalid[tn] = (n < NTOT);
        int nc = nvalid[tn] ? n : NTOT - 1;
        int q  = nc / IJ;
        int j  = nc - q * IJ;
        rqv[tn]   = qn[nc];
        obase[tn] = (size_t)q * OUTQ + j;
    }
    #pragma unroll
    for (int tm = 0; tm < 4; ++tm) {
        #pragma unroll
        for (int rr = 0; rr < 4; ++rr) {
            int m = m0 + wm0 + tm * 16 + fq * 4 + rr;
            if (m < MROWS) {
                float rp = pn[m];
                #pragma unroll
                for (int tn = 0; tn < 4; ++tn) {
                    if (nvalid[tn]) {
                        float d = fmaxf(rp * rqv[tn], EPSV);
                        out[obase[tn] + (size_t)m * IJ] =
                            acc[tm][tn][rr] * __builtin_amdgcn_rcpf(d);
                    }
                }
            }
        }
    }
}

// ---------------------------------------------------------------------------
// Fallback (round-1 kernel, known-passing) if ws_size is insufficient.
// ---------------------------------------------------------------------------
#define BMF 128
#define BNF 224
#define LPAD 40
__global__ __launch_bounds__(512, 4)
void sim_fallback(const float* __restrict__ proto,
                  const float* __restrict__ query,
                  float* __restrict__ out)
{
    __shared__ unsigned short As[BMF][LPAD];
    __shared__ unsigned short Bs[BNF][LPAD];
    __shared__ float redA[4][BMF];
    __shared__ float redB[2][BNF];
    __shared__ float rpS[BMF];
    __shared__ float rqS[BNF];

    const int tid = threadIdx.x;
    const int m0  = blockIdx.x * BMF;
    const int q   = blockIdx.y;

    const int mA  = tid & (BMF - 1);
    const int krA = tid >> 7;
    const int wiA = m0 + mA;
    const bool va = (wiA < MROWS);
    const int wA  = va ? (wiA / IJ) : 0;
    const int iA  = va ? (wiA - wA * IJ) : 0;
    const float* pA = proto + wA * (CD * IJ) + iA;

    const bool tb  = (tid < 448);
    const int jB   = tb ? (tid % BNF) : 0;
    const int krB  = tb ? (tid / BNF) : 0;
    const bool vb  = tb && (jB < IJ);
    const float* qB = query + q * (CD * IJ) + jB;

    float ssA = 0.f, ssB = 0.f;

    const int wv   = tid >> 6;
    const int lane = tid & 63;
    const int wm0  = (wv >> 1) * 32;
    const int wn0  = (wv & 1) * 112;
    const int fr   = lane & 15;
    const int fq   = lane >> 4;

    f32x4 acc[2][7];
    #pragma unroll
    for (int a = 0; a < 2; a++)
        #pragma unroll
        for (int b = 0; b < 7; b++)
            acc[a][b] = (f32x4){0.f, 0.f, 0.f, 0.f};

    for (int it = 0; it < CD / 32; ++it) {
        const int c0 = it * 32;
        {
            float v[8];
            #pragma unroll
            for (int e = 0; e < 8; e++) {
                int c = c0 + krA * 8 + e;
                v[e] = va ? pA[c * IJ] : 0.f;
            }
            #pragma unroll
            for (int e = 0; e < 8; e++) ssA += v[e] * v[e];
            union { unsigned short s[8]; uint4 u; } pk;
            #pragma unroll
            for (int e = 0; e < 8; e++) pk.s[e] = f2bf(v[e]);
            *(uint4*)&As[mA][krA * 8] = pk.u;
        }
        if (tb) {
            #pragma unroll
            for (int h = 0; h < 2; ++h) {
                float v[8];
                #pragma unroll
                for (int e = 0; e < 8; e++) {
                    int c = c0 + krB * 16 + h * 8 + e;
                    v[e] = vb ? qB[c * IJ] : 0.f;
                }
                #pragma unroll
                for (int e = 0; e < 8; e++) ssB += v[e] * v[e];
                union { unsigned short s[8]; uint4 u; } pk;
                #pragma unroll
                for (int e = 0; e < 8; e++) pk.s[e] = f2bf(v[e]);
                *(uint4*)&Bs[jB][krB * 16 + h * 8] = pk.u;
            }
        }
        __syncthreads();
        bf16x8 af[2], bfv[7];
        #pragma unroll
        for (int tm = 0; tm < 2; tm++)
            af[tm] = *(const bf16x8*)&As[wm0 + tm * 16 + fr][fq * 8];
        #pragma unroll
        for (int tn = 0; tn < 7; tn++)
            bfv[tn] = *(const bf16x8*)&Bs[wn0 + tn * 16 + fr][fq * 8];
        #pragma unroll
        for (int tm = 0; tm < 2; tm++)
            #pragma unroll
            for (int tn = 0; tn < 7; tn++)
                acc[tm][tn] = __builtin_amdgcn_mfma_f32_16x16x32_bf16(
                    af[tm], bfv[tn], acc[tm][tn], 0, 0, 0);
        __syncthreads();
    }

    redA[krA][mA] = ssA;
    if (tb) redB[krB][jB] = ssB;
    __syncthreads();
    if (tid < BMF) {
        rpS[tid] = sqrtf(redA[0][tid] + redA[1][tid] + redA[2][tid] + redA[3][tid]);
    } else if (tid >= 256 && tid < 256 + BNF) {
        int j = tid - 256;
        rqS[j] = sqrtf(redB[0][j] + redB[1][j]);
    }
    __syncthreads();

    #pragma unroll
    for (int tm = 0; tm < 2; tm++) {
        #pragma unroll
        for (int tn = 0; tn < 7; tn++) {
            #pragma unroll
            for (int r = 0; r < 4; r++) {
                int rl = wm0 + tm * 16 + fq * 4 + r;
                int cl = wn0 + tn * 16 + fr;
                int wi = m0 + rl;
                if (wi < MROWS && cl < IJ) {
                    float denom = fmaxf(rpS[rl] * rqS[cl], 1e-8f);
                    out[(size_t)(q * MROWS + wi) * IJ + cl] = acc[tm][tn][r] / denom;
                }
            }
        }
    }
}

// ---------------------------------------------------------------------------
extern "C" void kernel_launch(void* const* d_in, const int* in_sizes, int n_in,
                              void* d_out, int out_size, void* d_ws, size_t ws_size,
                              hipStream_t stream) {
    const float* proto = (const float*)d_in[0];
    const float* query = (const float*)d_in[1];
    float* out = (float*)d_out;

    // workspace layout
    const size_t off_pT = 0;                       // 1960*640*2 = 2,508,800
    const size_t off_qT = 2508800;                 // 58800*640*2 = 75,264,000
    const size_t off_pn = 77772800;                // 1960*4
    const size_t off_qn = 77780736;                // 58800*4
    const size_t need   = 78015936;

    if (ws_size < need) {
        dim3 grid((MROWS + BMF - 1) / BMF, QN);
        sim_fallback<<<grid, 512, 0, stream>>>(proto, query, out);
        return;
    }

    char* ws = (char*)d_ws;
    uint4* pT = (uint4*)(ws + off_pT);
    uint4* qT = (uint4*)(ws + off_qT);
    float* pn = (float*)(ws + off_pn);
    float* qn = (float*)(ws + off_qn);

    prep_kernel<<<dim3(13, QN), 256, 0, stream>>>(query, qT, qn);
    prep_kernel<<<dim3(13, WN), 256, 0, stream>>>(proto, pT, pn);

    gemm_kernel<<<dim3(NWG), 512, 0, stream>>>(pT, qT, pn, qn, out);
}

// Round 5
// 393.299 us; speedup vs baseline: 1.2804x; 1.1015x over previous
//
#include <hip/hip_runtime.h>
#include <stdint.h>

#define QN    300
#define WN    10
#define CD    640
#define IJ    196
#define MROWS 1960              // WN*IJ
#define NTOT  58800             // QN*IJ
#define OUTQ  384160            // MROWS*IJ
#define EPSV  1e-8f

#define BM    256
#define BN    256
#define BK    64
#define BUFE  ((BM + BN) * BK)         // 32768 ushorts = 64 KB per buffer
#define NTK   (CD / BK)                // 10 K-tiles

#define MT_TILES 8                     // m tiles of 256 (pad 2048)
#define NT_TILES 230                   // n tiles of 256 (pad 58880)
#define NWG      (MT_TILES * NT_TILES) // 1840, divisible by 8
#define CPX      (NWG / 8)             // 230

typedef __attribute__((ext_vector_type(8))) short bf16x8;
typedef __attribute__((ext_vector_type(4))) float f32x4;

__device__ __forceinline__ unsigned short f2bf(float f) {
    uint32_t u = __float_as_uint(f);
    u += 0x7FFFu + ((u >> 16) & 1u);   // RNE
    return (unsigned short)(u >> 16);
}

__device__ __forceinline__ void gload16(const void* g, void* l) {
    __builtin_amdgcn_global_load_lds(
        (const __attribute__((address_space(1))) void*)g,
        (__attribute__((address_space(3))) void*)l,
        16, 0, 0);
}

// ---------------------------------------------------------------------------
// Pre-pass: X[B][640][196] fp32 -> XT[B*196][640] bf16 (k contiguous), with
// the 3-bit swizzle baked per 16B unit within each 8-unit (64-elem) K-group:
// stored_unit = (u&8) | ((u&7) ^ (row&7)).  Also fp32 norms.
// ---------------------------------------------------------------------------
__global__ __launch_bounds__(256)
void prep_kernel(const float* __restrict__ X, uint4* __restrict__ XT,
                 float* __restrict__ nrm)
{
    __shared__ float T[128][21];
    __shared__ float ssL[16][17];

    const int b  = blockIdx.y;
    const int i0 = blockIdx.x * 16;
    const int t  = threadIdx.x;
    const float* Xb = X + (size_t)b * (CD * IJ);

    const int cA  = t >> 2;              // 0..63
    const int i4  = (t & 3) * 4;         // 0,4,8,12
    const int iv  = i0 + i4;
    const bool liv = (iv <= IJ - 4);

    const int il = t >> 4;               // 0..15
    const int u  = t & 15;               // 0..15
    float ss = 0.f;

    const int ig   = i0 + il;
    const bool wok = (ig < IJ);
    const int rowg = b * IJ + (wok ? ig : IJ - 1);
    const int uxor = rowg & 7;

    for (int cc = 0; cc < CD / 128; ++cc) {
        #pragma unroll
        for (int pass = 0; pass < 2; ++pass) {
            int cl = pass * 64 + cA;
            int c  = cc * 128 + cl;
            float4 v = make_float4(0.f, 0.f, 0.f, 0.f);
            if (liv) v = *(const float4*)&Xb[(size_t)c * IJ + iv];
            T[cl][i4 + 0] = v.x; T[cl][i4 + 1] = v.y;
            T[cl][i4 + 2] = v.z; T[cl][i4 + 3] = v.w;
        }
        __syncthreads();
        float v[8];
        #pragma unroll
        for (int r = 0; r < 8; ++r) { v[r] = T[u * 8 + r][il]; ss += v[r] * v[r]; }
        if (wok) {
            union { unsigned short s[8]; uint4 q; } pk;
            #pragma unroll
            for (int r = 0; r < 8; ++r) pk.s[r] = f2bf(v[r]);
            int us = (u & 8) | ((u & 7) ^ uxor);
            XT[(size_t)rowg * (CD / 8) + cc * 16 + us] = pk.q;
        }
        __syncthreads();
    }

    ssL[il][u] = ss;
    __syncthreads();
    if (t < 16) {
        int igw = i0 + t;
        if (igw < IJ) {
            float s = 0.f;
            #pragma unroll
            for (int k = 0; k < 16; ++k) s += ssL[t][k];
            nrm[b * IJ + igw] = sqrtf(s);
        }
    }
}

// ---------------------------------------------------------------------------
// GEMM: C[m][n] = sum_c AT[m][c]*BT[n][c].  256x256 tile, BK=64, 8 waves
// (2M x 4N), per-wave 128x64 output (acc[8][4] of 16x16x32).  4-phase
// schedule per K-tile (m201-style): each phase {ds_read quadrant | issue
// global_load_lds of tile t+1 | barrier | lgkmcnt(0) | setprio(1) 16 MFMA
// setprio(0) | barrier}.  vmcnt(0) only at the tile boundary (last staging
// load has ~2 phases of cover).  2-deep 128 KB LDS double buffer.
// Pre-swizzled global + XOR ds_read (0 bank conflicts), bijective XCD
// swizzle m-fast (B-panel L2 reuse).
// ---------------------------------------------------------------------------
__global__ __launch_bounds__(512, 2)
void gemm_kernel(const uint4* __restrict__ AT, const uint4* __restrict__ BT,
                 const float* __restrict__ pn, const float* __restrict__ qn,
                 float* __restrict__ out)
{
    __shared__ unsigned short lds[2 * BUFE];   // 128 KB

    const int bid = blockIdx.x;
    const int swz = (bid & 7) * CPX + (bid >> 3);   // bijective (1840%8==0)
    const int mt  = swz & (MT_TILES - 1);
    const int nt  = swz >> 3;
    const int m0  = mt * BM;
    const int n0  = nt * BN;

    const int t  = threadIdx.x;
    const int w  = t >> 6, l = t & 63;
    const int fr = l & 15, fq = l >> 4;
    const int wm0 = (w >> 2) * 128;   // 2 M-waves
    const int wn0 = (w & 3) * 64;     // 4 N-waves

    // ---- staging pointers (advance by 8 uint4 per staged K-tile)
    const int lr = l >> 3, lu = l & 7;
    int ra00 = m0 +   0 + w * 8 + lr; if (ra00 > MROWS - 1) ra00 = MROWS - 1;
    int ra01 = m0 +  64 + w * 8 + lr; if (ra01 > MROWS - 1) ra01 = MROWS - 1;
    int ra10 = m0 + 128 + w * 8 + lr; if (ra10 > MROWS - 1) ra10 = MROWS - 1;
    int ra11 = m0 + 192 + w * 8 + lr; if (ra11 > MROWS - 1) ra11 = MROWS - 1;
    int rb00 = n0 +   0 + w * 8 + lr; if (rb00 > NTOT - 1) rb00 = NTOT - 1;
    int rb01 = n0 +  64 + w * 8 + lr; if (rb01 > NTOT - 1) rb01 = NTOT - 1;
    int rb10 = n0 + 128 + w * 8 + lr; if (rb10 > NTOT - 1) rb10 = NTOT - 1;
    int rb11 = n0 + 192 + w * 8 + lr; if (rb11 > NTOT - 1) rb11 = NTOT - 1;
    const uint4* ga00 = AT + (size_t)ra00 * 80 + lu;
    const uint4* ga01 = AT + (size_t)ra01 * 80 + lu;
    const uint4* ga10 = AT + (size_t)ra10 * 80 + lu;
    const uint4* ga11 = AT + (size_t)ra11 * 80 + lu;
    const uint4* gb00 = BT + (size_t)rb00 * 80 + lu;
    const uint4* gb01 = BT + (size_t)rb01 * 80 + lu;
    const uint4* gb10 = BT + (size_t)rb10 * 80 + lu;
    const uint4* gb11 = BT + (size_t)rb11 * 80 + lu;
    // wave-uniform LDS element offsets (HW adds lane*16B)
    const int la00 = (  0 + w * 8) * 64;
    const int la01 = ( 64 + w * 8) * 64;
    const int la10 = (128 + w * 8) * 64;
    const int la11 = (192 + w * 8) * 64;
    const int lb00 = BM * 64 + (  0 + w * 8) * 64;
    const int lb01 = BM * 64 + ( 64 + w * 8) * 64;
    const int lb10 = BM * 64 + (128 + w * 8) * 64;
    const int lb11 = BM * 64 + (192 + w * 8) * 64;

    // ---- fragment read offsets (loop-invariant); elem-unit XOR pre-shifted
    const int fqS0 = fq << 3;
    const int fqS1 = (fq + 4) << 3;
    int baA[8], kyA[8], baB[4], kyB[4];
    #pragma unroll
    for (int i = 0; i < 8; ++i) {
        int rowa = wm0 + i * 16 + fr;
        baA[i] = rowa * 64;  kyA[i] = (rowa & 7) << 3;
    }
    #pragma unroll
    for (int i = 0; i < 4; ++i) {
        int rowb = wn0 + i * 16 + fr;
        baB[i] = BM * 64 + rowb * 64;  kyB[i] = (rowb & 7) << 3;
    }

    f32x4 acc[8][4];
    #pragma unroll
    for (int a = 0; a < 8; ++a)
        #pragma unroll
        for (int bb = 0; bb < 4; ++bb)
            acc[a][bb] = (f32x4){0.f, 0.f, 0.f, 0.f};

#define STAGE_A(OFF)                                                      \
    gload16(ga00, (char*)&lds[(OFF) + la00]); ga00 += 8;                  \
    gload16(ga01, (char*)&lds[(OFF) + la01]); ga01 += 8;                  \
    gload16(ga10, (char*)&lds[(OFF) + la10]); ga10 += 8;                  \
    gload16(ga11, (char*)&lds[(OFF) + la11]); ga11 += 8;
#define STAGE_B0(OFF)                                                     \
    gload16(gb00, (char*)&lds[(OFF) + lb00]); gb00 += 8;                  \
    gload16(gb01, (char*)&lds[(OFF) + lb01]); gb01 += 8;
#define STAGE_B1(OFF)                                                     \
    gload16(gb10, (char*)&lds[(OFF) + lb10]); gb10 += 8;                  \
    gload16(gb11, (char*)&lds[(OFF) + lb11]); gb11 += 8;

#define BARRIER  __builtin_amdgcn_s_barrier()
#define LGKM0    do { asm volatile("s_waitcnt lgkmcnt(0)" ::: "memory");  \
                      __builtin_amdgcn_sched_barrier(0); } while (0)
#define VMCNT0   asm volatile("s_waitcnt vmcnt(0)" ::: "memory")

#define MFMA_Q(MB, BF)                                                    \
    _Pragma("unroll")                                                     \
    for (int mm = 0; mm < 4; ++mm)                                        \
        _Pragma("unroll")                                                 \
        for (int nn = 0; nn < 4; ++nn)                                    \
            acc[(MB) + mm][nn] = __builtin_amdgcn_mfma_f32_16x16x32_bf16( \
                af[mm], BF[nn], acc[(MB) + mm][nn], 0, 0, 0);

#define TILE(STG)                                                         \
  { bf16x8 af[4], bf0[4], bf1[4];                                         \
    /* ---- phase 0: ks0, M-frags 0-3; stage A of t+1 */                  \
    _Pragma("unroll")                                                     \
    for (int mm = 0; mm < 4; ++mm)                                        \
        af[mm] = *(const bf16x8*)&lds[oc + baA[mm] + (fqS0 ^ kyA[mm])];   \
    _Pragma("unroll")                                                     \
    for (int nn = 0; nn < 4; ++nn)                                        \
        bf0[nn] = *(const bf16x8*)&lds[oc + baB[nn] + (fqS0 ^ kyB[nn])];  \
    if (STG) { STAGE_A(os); }                                             \
    BARRIER; LGKM0;                                                       \
    __builtin_amdgcn_s_setprio(1); MFMA_Q(0, bf0);                        \
    __builtin_amdgcn_s_setprio(0); BARRIER;                               \
    /* ---- phase 1: ks0, M-frags 4-7; stage B-half0 */                   \
    _Pragma("unroll")                                                     \
    for (int mm = 0; mm < 4; ++mm)                                        \
        af[mm] = *(const bf16x8*)&lds[oc + baA[4+mm] + (fqS0 ^ kyA[4+mm])];\
    if (STG) { STAGE_B0(os); }                                            \
    BARRIER; LGKM0;                                                       \
    __builtin_amdgcn_s_setprio(1); MFMA_Q(4, bf0);                        \
    __builtin_amdgcn_s_setprio(0); BARRIER;                               \
    /* ---- phase 2: ks1, M-frags 0-3; stage B-half1 */                   \
    _Pragma("unroll")                                                     \
    for (int mm = 0; mm < 4; ++mm)                                        \
        af[mm] = *(const bf16x8*)&lds[oc + baA[mm] + (fqS1 ^ kyA[mm])];   \
    _Pragma("unroll")                                                     \
    for (int nn = 0; nn < 4; ++nn)                                        \
        bf1[nn] = *(const bf16x8*)&lds[oc + baB[nn] + (fqS1 ^ kyB[nn])];  \
    if (STG) { STAGE_B1(os); }                                            \
    BARRIER; LGKM0;                                                       \
    __builtin_amdgcn_s_setprio(1); MFMA_Q(0, bf1);                        \
    __builtin_amdgcn_s_setprio(0); BARRIER;                               \
    /* ---- phase 3: ks1, M-frags 4-7; tile-boundary vmcnt drain */       \
    _Pragma("unroll")                                                     \
    for (int mm = 0; mm < 4; ++mm)                                        \
        af[mm] = *(const bf16x8*)&lds[oc + baA[4+mm] + (fqS1 ^ kyA[4+mm])];\
    BARRIER; LGKM0;                                                       \
    __builtin_amdgcn_s_setprio(1); MFMA_Q(4, bf1);                        \
    __builtin_amdgcn_s_setprio(0);                                        \
    VMCNT0; BARRIER;                                                      \
    int tswp = oc; oc = os; os = tswp;                                    \
  }

    // ---- prologue: stage tile 0 into buf 0, wait, barrier
    STAGE_A(0); STAGE_B0(0); STAGE_B1(0);
    VMCNT0;
    BARRIER;

    int oc = 0, os = BUFE;
    for (int tt = 0; tt < NTK - 1; ++tt) {
        TILE(1)
    }
    TILE(0)

#undef TILE
#undef MFMA_Q
#undef STAGE_A
#undef STAGE_B0
#undef STAGE_B1

    // ---- epilogue: out[q*OUTQ + m*196 + j] = acc / max(rp*rq, eps)
    float  rqv[4];
    int    nvalid[4];
    size_t obase[4];
    #pragma unroll
    for (int tn = 0; tn < 4; ++tn) {
        int n = n0 + wn0 + tn * 16 + fr;
        nvalid[tn] = (n < NTOT);
        int nc = nvalid[tn] ? n : NTOT - 1;
        int q  = nc / IJ;
        int j  = nc - q * IJ;
        rqv[tn]   = qn[nc];
        obase[tn] = (size_t)q * OUTQ + j;
    }
    #pragma unroll
    for (int tm = 0; tm < 8; ++tm) {
        #pragma unroll
        for (int rr = 0; rr < 4; ++rr) {
            int m = m0 + wm0 + tm * 16 + fq * 4 + rr;
            if (m < MROWS) {
                float rp = pn[m];
                #pragma unroll
                for (int tn = 0; tn < 4; ++tn) {
                    if (nvalid[tn]) {
                        float d = fmaxf(rp * rqv[tn], EPSV);
                        out[obase[tn] + (size_t)m * IJ] =
                            acc[tm][tn][rr] * __builtin_amdgcn_rcpf(d);
                    }
                }
            }
        }
    }
}

// ---------------------------------------------------------------------------
// Fallback (round-1 kernel, known-passing) if ws_size is insufficient.
// ---------------------------------------------------------------------------
#define BMF 128
#define BNF 224
#define LPAD 40
__global__ __launch_bounds__(512, 4)
void sim_fallback(const float* __restrict__ proto,
                  const float* __restrict__ query,
                  float* __restrict__ out)
{
    __shared__ unsigned short As[BMF][LPAD];
    __shared__ unsigned short Bs[BNF][LPAD];
    __shared__ float redA[4][BMF];
    __shared__ float redB[2][BNF];
    __shared__ float rpS[BMF];
    __shared__ float rqS[BNF];

    const int tid = threadIdx.x;
    const int m0  = blockIdx.x * BMF;
    const int q   = blockIdx.y;

    const int mA  = tid & (BMF - 1);
    const int krA = tid >> 7;
    const int wiA = m0 + mA;
    const bool va = (wiA < MROWS);
    const int wA  = va ? (wiA / IJ) : 0;
    const int iA  = va ? (wiA - wA * IJ) : 0;
    const float* pA = proto + wA * (CD * IJ) + iA;

    const bool tb  = (tid < 448);
    const int jB   = tb ? (tid % BNF) : 0;
    const int krB  = tb ? (tid / BNF) : 0;
    const bool vb  = tb && (jB < IJ);
    const float* qB = query + q * (CD * IJ) + jB;

    float ssA = 0.f, ssB = 0.f;

    const int wv   = tid >> 6;
    const int lane = tid & 63;
    const int wm0  = (wv >> 1) * 32;
    const int wn0  = (wv & 1) * 112;
    const int fr   = lane & 15;
    const int fq   = lane >> 4;

    f32x4 acc[2][7];
    #pragma unroll
    for (int a = 0; a < 2; a++)
        #pragma unroll
        for (int b = 0; b < 7; b++)
            acc[a][b] = (f32x4){0.f, 0.f, 0.f, 0.f};

    for (int it = 0; it < CD / 32; ++it) {
        const int c0 = it * 32;
        {
            float v[8];
            #pragma unroll
            for (int e = 0; e < 8; e++) {
                int c = c0 + krA * 8 + e;
                v[e] = va ? pA[c * IJ] : 0.f;
            }
            #pragma unroll
            for (int e = 0; e < 8; e++) ssA += v[e] * v[e];
            union { unsigned short s[8]; uint4 u; } pk;
            #pragma unroll
            for (int e = 0; e < 8; e++) pk.s[e] = f2bf(v[e]);
            *(uint4*)&As[mA][krA * 8] = pk.u;
        }
        if (tb) {
            #pragma unroll
            for (int h = 0; h < 2; ++h) {
                float v[8];
                #pragma unroll
                for (int e = 0; e < 8; e++) {
                    int c = c0 + krB * 16 + h * 8 + e;
                    v[e] = vb ? qB[c * IJ] : 0.f;
                }
                #pragma unroll
                for (int e = 0; e < 8; e++) ssB += v[e] * v[e];
                union { unsigned short s[8]; uint4 u; } pk;
                #pragma unroll
                for (int e = 0; e < 8; e++) pk.s[e] = f2bf(v[e]);
                *(uint4*)&Bs[jB][krB * 16 + h * 8] = pk.u;
            }
        }
        __syncthreads();
        bf16x8 af[2], bfv[7];
        #pragma unroll
        for (int tm = 0; tm < 2; tm++)
            af[tm] = *(const bf16x8*)&As[wm0 + tm * 16 + fr][fq * 8];
        #pragma unroll
        for (int tn = 0; tn < 7; tn++)
            bfv[tn] = *(const bf16x8*)&Bs[wn0 + tn * 16 + fr][fq * 8];
        #pragma unroll
        for (int tm = 0; tm < 2; tm++)
            #pragma unroll
            for (int tn = 0; tn < 7; tn++)
                acc[tm][tn] = __builtin_amdgcn_mfma_f32_16x16x32_bf16(
                    af[tm], bfv[tn], acc[tm][tn], 0, 0, 0);
        __syncthreads();
    }

    redA[krA][mA] = ssA;
    if (tb) redB[krB][jB] = ssB;
    __syncthreads();
    if (tid < BMF) {
        rpS[tid] = sqrtf(redA[0][tid] + redA[1][tid] + redA[2][tid] + redA[3][tid]);
    } else if (tid >= 256 && tid < 256 + BNF) {
        int j = tid - 256;
        rqS[j] = sqrtf(redB[0][j] + redB[1][j]);
    }
    __syncthreads();

    #pragma unroll
    for (int tm = 0; tm < 2; tm++) {
        #pragma unroll
        for (int tn = 0; tn < 7; tn++) {
            #pragma unroll
            for (int r = 0; r < 4; r++) {
                int rl = wm0 + tm * 16 + fq * 4 + r;
                int cl = wn0 + tn * 16 + fr;
                int wi = m0 + rl;
                if (wi < MROWS && cl < IJ) {
                    float denom = fmaxf(rpS[rl] * rqS[cl], 1e-8f);
                    out[(size_t)(q * MROWS + wi) * IJ + cl] = acc[tm][tn][r] / denom;
                }
            }
        }
    }
}

// ---------------------------------------------------------------------------
extern "C" void kernel_launch(void* const* d_in, const int* in_sizes, int n_in,
                              void* d_out, int out_size, void* d_ws, size_t ws_size,
                              hipStream_t stream) {
    const float* proto = (const float*)d_in[0];
    const float* query = (const float*)d_in[1];
    float* out = (float*)d_out;

    // workspace layout
    const size_t off_pT = 0;                       // 1960*640*2 = 2,508,800
    const size_t off_qT = 2508800;                 // 58800*640*2 = 75,264,000
    const size_t off_pn = 77772800;                // 1960*4
    const size_t off_qn = 77780736;                // 58800*4
    const size_t need   = 78015936;

    if (ws_size < need) {
        dim3 grid((MROWS + BMF - 1) / BMF, QN);
        sim_fallback<<<grid, 512, 0, stream>>>(proto, query, out);
        return;
    }

    char* ws = (char*)d_ws;
    uint4* pT = (uint4*)(ws + off_pT);
    uint4* qT = (uint4*)(ws + off_qT);
    float* pn = (float*)(ws + off_pn);
    float* qn = (float*)(ws + off_qn);

    prep_kernel<<<dim3(13, QN), 256, 0, stream>>>(query, qT, qn);
    prep_kernel<<<dim3(13, WN), 256, 0, stream>>>(proto, pT, pn);

    gemm_kernel<<<dim3(NWG), 512, 0, stream>>>(pT, qT, pn, qn, out);
}

// Round 7
// 392.966 us; speedup vs baseline: 1.2815x; 1.0008x over previous
//
#include <hip/hip_runtime.h>
#include <stdint.h>

#define QN    300
#define WN    10
#define CD    640
#define IJ    196
#define MROWS 1960              // WN*IJ
#define NTOT  58800             // QN*IJ
#define OUTQ  384160            // MROWS*IJ
#define EPSV  1e-8f

#define BM    256
#define BN    256
#define BK    64
#define BUFE  ((BM + BN) * BK)         // 32768 ushorts = 64 KB per buffer
#define NTK   (CD / BK)                // 10 K-tiles

#define MT_TILES 8                     // m tiles of 256 (pad 2048)
#define NT_TILES 230                   // n tiles of 256 (pad 58880)
#define NWG      (MT_TILES * NT_TILES) // 1840, divisible by 8
#define CPX      (NWG / 8)             // 230

typedef __attribute__((ext_vector_type(8))) short bf16x8;
typedef __attribute__((ext_vector_type(4))) float f32x4;

__device__ __forceinline__ unsigned short f2bf(float f) {
    uint32_t u = __float_as_uint(f);
    u += 0x7FFFu + ((u >> 16) & 1u);   // RNE
    return (unsigned short)(u >> 16);
}

__device__ __forceinline__ void gload16(const void* g, void* l) {
    __builtin_amdgcn_global_load_lds(
        (const __attribute__((address_space(1))) void*)g,
        (__attribute__((address_space(3))) void*)l,
        16, 0, 0);
}

// ---------------------------------------------------------------------------
// Pre-pass: X[B][640][196] fp32 -> XT[B*196][640] bf16 (k contiguous), with
// the 3-bit swizzle baked per 16B unit within each 8-unit (64-elem) K-group:
// stored_unit = (u&8) | ((u&7) ^ (row&7)).  Also fp32 norms.
// ---------------------------------------------------------------------------
__global__ __launch_bounds__(256)
void prep_kernel(const float* __restrict__ X, uint4* __restrict__ XT,
                 float* __restrict__ nrm)
{
    __shared__ float T[128][21];
    __shared__ float ssL[16][17];

    const int b  = blockIdx.y;
    const int i0 = blockIdx.x * 16;
    const int t  = threadIdx.x;
    const float* Xb = X + (size_t)b * (CD * IJ);

    const int cA  = t >> 2;              // 0..63
    const int i4  = (t & 3) * 4;         // 0,4,8,12
    const int iv  = i0 + i4;
    const bool liv = (iv <= IJ - 4);

    const int il = t >> 4;               // 0..15
    const int u  = t & 15;               // 0..15
    float ss = 0.f;

    const int ig   = i0 + il;
    const bool wok = (ig < IJ);
    const int rowg = b * IJ + (wok ? ig : IJ - 1);
    const int uxor = rowg & 7;

    for (int cc = 0; cc < CD / 128; ++cc) {
        #pragma unroll
        for (int pass = 0; pass < 2; ++pass) {
            int cl = pass * 64 + cA;
            int c  = cc * 128 + cl;
            float4 v = make_float4(0.f, 0.f, 0.f, 0.f);
            if (liv) v = *(const float4*)&Xb[(size_t)c * IJ + iv];
            T[cl][i4 + 0] = v.x; T[cl][i4 + 1] = v.y;
            T[cl][i4 + 2] = v.z; T[cl][i4 + 3] = v.w;
        }
        __syncthreads();
        float v[8];
        #pragma unroll
        for (int r = 0; r < 8; ++r) { v[r] = T[u * 8 + r][il]; ss += v[r] * v[r]; }
        if (wok) {
            union { unsigned short s[8]; uint4 q; } pk;
            #pragma unroll
            for (int r = 0; r < 8; ++r) pk.s[r] = f2bf(v[r]);
            int us = (u & 8) | ((u & 7) ^ uxor);
            XT[(size_t)rowg * (CD / 8) + cc * 16 + us] = pk.q;
        }
        __syncthreads();
    }

    ssL[il][u] = ss;
    __syncthreads();
    if (t < 16) {
        int igw = i0 + t;
        if (igw < IJ) {
            float s = 0.f;
            #pragma unroll
            for (int k = 0; k < 16; ++k) s += ssL[t][k];
            nrm[b * IJ + igw] = sqrtf(s);
        }
    }
}

// ---------------------------------------------------------------------------
// GEMM: C[m][n] = sum_c AT[m][c]*BT[n][c].  256x256 tile, BK=64, 8 waves
// (2M x 4N), per-wave 128x64 (acc[8][4] of 16x16x32).
//
// 8-phase / 2-K-tiles-per-iteration schedule with counted vmcnt (T3+T4).
// KEY INVARIANT (fixes round-6 race): every wave's fragment reads span ALL
// FOUR staged halves of a tile (wave's wm0/wn0 select rows in A0 or A1, B0
// or B1), so a tile must be FULLY landed before its first phase, and a
// stage may target a buffer only >=1 barrier after that buffer's last
// ds_read completed (lgkmcnt(0) precedes each phase's MFMA and barrier).
//
// Stage placement (iter i: even tile e=2i in buf0, odd o=2i+1 in buf1):
//   e.P1: rd A0-3,B0-1(buf0)  st B0(o)->buf1      (other buf, dead since
//   e.P2: rd B2-3(buf0)       st A1(o)->buf1       prev iter's o.P3)
//   e.P3: rd A4-7(buf0)       st B1(o)->buf1
//   e.P4: (regs only)         st A0(e+2)->buf0    (own buf; all buf0 reads
//                             VMC(2)               done at e.P3's lgkm+bar)
//   o.P5-P8: mirror (stages -> buf0, A0(o+2)->buf1, VMC(2))
// vmcnt gate audit (loads/wave outstanding at each VMC(2)):
//   prologue 10 -> VMC(2): tile0's 8 landed, t1-A0 in flight.
//   steady: +2/+2/+2/+2 -> 10 -> VMC(2): tile t+1 fully landed, 2 in flight.
//   vmcnt NEVER 0 inside the loop.  Tail stages (tiles 10,11) are benign
//   in-ws OOB reads, written to dead LDS, never consumed.
// ---------------------------------------------------------------------------
__global__ __launch_bounds__(512, 2)
void gemm_kernel(const uint4* __restrict__ AT, const uint4* __restrict__ BT,
                 const float* __restrict__ pn, const float* __restrict__ qn,
                 float* __restrict__ out)
{
    __shared__ unsigned short lds[2 * BUFE];   // 128 KB

    const int bid = blockIdx.x;
    const int swz = (bid & 7) * CPX + (bid >> 3);   // bijective (1840%8==0)
    const int mt  = swz & (MT_TILES - 1);
    const int nt  = swz >> 3;
    const int m0  = mt * BM;
    const int n0  = nt * BN;

    const int t  = threadIdx.x;
    const int w  = t >> 6, l = t & 63;
    const int fr = l & 15, fq = l >> 4;
    const int wm0 = (w >> 2) * 128;   // 2 M-waves
    const int wn0 = (w & 3) * 64;     // 4 N-waves

    // ---- staging pointers (each stream staged once per K-tile it serves)
    const int lr = l >> 3, lu = l & 7;
    int ra00 = m0 +   0 + w * 8 + lr; if (ra00 > MROWS - 1) ra00 = MROWS - 1;
    int ra01 = m0 +  64 + w * 8 + lr; if (ra01 > MROWS - 1) ra01 = MROWS - 1;
    int ra10 = m0 + 128 + w * 8 + lr; if (ra10 > MROWS - 1) ra10 = MROWS - 1;
    int ra11 = m0 + 192 + w * 8 + lr; if (ra11 > MROWS - 1) ra11 = MROWS - 1;
    int rb00 = n0 +   0 + w * 8 + lr; if (rb00 > NTOT - 1) rb00 = NTOT - 1;
    int rb01 = n0 +  64 + w * 8 + lr; if (rb01 > NTOT - 1) rb01 = NTOT - 1;
    int rb10 = n0 + 128 + w * 8 + lr; if (rb10 > NTOT - 1) rb10 = NTOT - 1;
    int rb11 = n0 + 192 + w * 8 + lr; if (rb11 > NTOT - 1) rb11 = NTOT - 1;
    const uint4* ga00 = AT + (size_t)ra00 * 80 + lu;
    const uint4* ga01 = AT + (size_t)ra01 * 80 + lu;
    const uint4* ga10 = AT + (size_t)ra10 * 80 + lu;
    const uint4* ga11 = AT + (size_t)ra11 * 80 + lu;
    const uint4* gb00 = BT + (size_t)rb00 * 80 + lu;
    const uint4* gb01 = BT + (size_t)rb01 * 80 + lu;
    const uint4* gb10 = BT + (size_t)rb10 * 80 + lu;
    const uint4* gb11 = BT + (size_t)rb11 * 80 + lu;
    // wave-uniform LDS element offsets (HW adds lane*16B)
    const int la00 = (  0 + w * 8) * 64;
    const int la01 = ( 64 + w * 8) * 64;
    const int la10 = (128 + w * 8) * 64;
    const int la11 = (192 + w * 8) * 64;
    const int lb00 = BM * 64 + (  0 + w * 8) * 64;
    const int lb01 = BM * 64 + ( 64 + w * 8) * 64;
    const int lb10 = BM * 64 + (128 + w * 8) * 64;
    const int lb11 = BM * 64 + (192 + w * 8) * 64;

    // ---- fragment read bases + swizzle keys (loop-invariant)
    const int fqS0 = fq << 3;
    const int fqS1 = (fq + 4) << 3;
    int baA[8], kyA[8], baB[4], kyB[4];
    #pragma unroll
    for (int i = 0; i < 8; ++i) {
        int rowa = wm0 + i * 16 + fr;
        baA[i] = rowa * 64;  kyA[i] = (rowa & 7) << 3;
    }
    #pragma unroll
    for (int i = 0; i < 4; ++i) {
        int rowb = wn0 + i * 16 + fr;
        baB[i] = BM * 64 + rowb * 64;  kyB[i] = (rowb & 7) << 3;
    }

    f32x4 acc[8][4];
    #pragma unroll
    for (int a = 0; a < 8; ++a)
        #pragma unroll
        for (int bb = 0; bb < 4; ++bb)
            acc[a][bb] = (f32x4){0.f, 0.f, 0.f, 0.f};

#define ST2(PA, PB, LA, LB)                                               \
    gload16(PA, (char*)&lds[(LA)]); PA += 8;                              \
    gload16(PB, (char*)&lds[(LB)]); PB += 8;

#define RD_A(OC, G)                                                       \
    _Pragma("unroll")                                                     \
    for (int mm = 0; mm < 4; ++mm) {                                      \
        af[mm]   = *(const bf16x8*)&lds[(OC) + baA[(G)+mm]                \
                                        + (fqS0 ^ kyA[(G)+mm])];          \
        af[4+mm] = *(const bf16x8*)&lds[(OC) + baA[(G)+mm]                \
                                        + (fqS1 ^ kyA[(G)+mm])];          \
    }
#define RD_B(BV, OC, G)                                                   \
    _Pragma("unroll")                                                     \
    for (int nn = 0; nn < 2; ++nn) {                                      \
        BV[nn]   = *(const bf16x8*)&lds[(OC) + baB[(G)+nn]                \
                                        + (fqS0 ^ kyB[(G)+nn])];          \
        BV[2+nn] = *(const bf16x8*)&lds[(OC) + baB[(G)+nn]                \
                                        + (fqS1 ^ kyB[(G)+nn])];          \
    }
#define MF(MB, NB, BV)                                                    \
    _Pragma("unroll")                                                     \
    for (int ks = 0; ks < 2; ++ks)                                        \
        _Pragma("unroll")                                                 \
        for (int mm = 0; mm < 4; ++mm)                                    \
            _Pragma("unroll")                                             \
            for (int nn = 0; nn < 2; ++nn)                                \
                acc[(MB)+mm][(NB)+nn] =                                   \
                    __builtin_amdgcn_mfma_f32_16x16x32_bf16(              \
                        af[ks*4+mm], BV[ks*2+nn],                         \
                        acc[(MB)+mm][(NB)+nn], 0, 0, 0);

#define BAR    __builtin_amdgcn_s_barrier()
#define LGKM0  do { asm volatile("s_waitcnt lgkmcnt(0)" ::: "memory");    \
                    __builtin_amdgcn_sched_barrier(0); } while (0)
#define VMC(N) asm volatile("s_waitcnt vmcnt(" #N ")" ::: "memory")
#define PRIO1  __builtin_amdgcn_s_setprio(1)
#define PRIO0  __builtin_amdgcn_s_setprio(0)

    // ---- prologue: tile0 fully -> buf0; tile1's A0 -> buf1.  10 loads;
    // VMC(2) -> tile0's 8 landed, tile1-A0 (2) still in flight.
    ST2(ga00, ga01, la00, la01);               // t0 A0
    ST2(gb00, gb01, lb00, lb01);               // t0 B0
    ST2(ga10, ga11, la10, la11);               // t0 A1
    ST2(gb10, gb11, lb10, lb11);               // t0 B1
    ST2(ga00, ga01, BUFE + la00, BUFE + la01); // t1 A0
    VMC(2); BAR;

    for (int i5 = 0; i5 < NTK / 2; ++i5) {
        bf16x8 af[8], b0[4], b1[4];
        // ======== even tile (buf0); stages -> buf1 (dead) except P4
        // P1: rd A0-3 + B0-1; st B0(odd)->buf1
        RD_A(0, 0); RD_B(b0, 0, 0);
        ST2(gb00, gb01, BUFE + lb00, BUFE + lb01);
        BAR; LGKM0;
        PRIO1; MF(0, 0, b0); PRIO0;
        BAR;
        // P2: rd B2-3; st A1(odd)->buf1
        RD_B(b1, 0, 2);
        ST2(ga10, ga11, BUFE + la10, BUFE + la11);
        BAR; LGKM0;
        PRIO1; MF(0, 2, b1); PRIO0;
        BAR;
        // P3: rd A4-7; st B1(odd)->buf1
        RD_A(0, 4);
        ST2(gb10, gb11, BUFE + lb10, BUFE + lb11);
        BAR; LGKM0;
        PRIO1; MF(4, 2, b1); PRIO0;
        BAR;
        // P4: regs only; st A0(even+2)->buf0 (all buf0 reads done at P3);
        //     counted gate: tile(odd) fully landed, 2 newest in flight.
        ST2(ga00, ga01, la00, la01);
        PRIO1; MF(4, 0, b0); PRIO0;
        VMC(2); BAR;
        // ======== odd tile (buf1); stages -> buf0 (dead) except P8
        // P5: rd A0-3 + B0-1; st B0(even+2)->buf0
        RD_A(BUFE, 0); RD_B(b0, BUFE, 0);
        ST2(gb00, gb01, lb00, lb01);
        BAR; LGKM0;
        PRIO1; MF(0, 0, b0); PRIO0;
        BAR;
        // P6: rd B2-3; st A1(even+2)->buf0
        RD_B(b1, BUFE, 2);
        ST2(ga10, ga11, la10, la11);
        BAR; LGKM0;
        PRIO1; MF(0, 2, b1); PRIO0;
        BAR;
        // P7: rd A4-7; st B1(even+2)->buf0
        RD_A(BUFE, 4);
        ST2(gb10, gb11, lb10, lb11);
        BAR; LGKM0;
        PRIO1; MF(4, 2, b1); PRIO0;
        BAR;
        // P8: st A0(odd+2)->buf1; counted gate for tile even+2
        ST2(ga00, ga01, BUFE + la00, BUFE + la01);
        PRIO1; MF(4, 0, b0); PRIO0;
        VMC(2); BAR;
    }

    VMC(0);   // drain tail garbage loads before epilogue/endpgm

#undef ST2
#undef RD_A
#undef RD_B
#undef MF
#undef BAR
#undef LGKM0
#undef VMC
#undef PRIO1
#undef PRIO0

    // ---- epilogue: out[q*OUTQ + m*196 + j] = acc / max(rp*rq, eps)
    float  rqv[4];
    int    nvalid[4];
    size_t obase[4];
    #pragma unroll
    for (int tn = 0; tn < 4; ++tn) {
        int n = n0 + wn0 + tn * 16 + fr;
        nvalid[tn] = (n < NTOT);
        int nc = nvalid[tn] ? n : NTOT - 1;
        int q  = nc / IJ;
        int j  = nc - q * IJ;
        rqv[tn]   = qn[nc];
        obase[tn] = (size_t)q * OUTQ + j;
    }
    #pragma unroll
    for (int tm = 0; tm < 8; ++tm) {
        #pragma unroll
        for (int rr = 0; rr < 4; ++rr) {
            int m = m0 + wm0 + tm * 16 + fq * 4 + rr;
            if (m < MROWS) {
                float rp = pn[m];
                #pragma unroll
                for (int tn = 0; tn < 4; ++tn) {
                    if (nvalid[tn]) {
                        float d = fmaxf(rp * rqv[tn], EPSV);
                        out[obase[tn] + (size_t)m * IJ] =
                            acc[tm][tn][rr] * __builtin_amdgcn_rcpf(d);
                    }
                }
            }
        }
    }
}

// ---------------------------------------------------------------------------
// Fallback (round-1 kernel, known-passing) if ws_size is insufficient.
// ---------------------------------------------------------------------------
#define BMF 128
#define BNF 224
#define LPAD 40
__global__ __launch_bounds__(512, 4)
void sim_fallback(const float* __restrict__ proto,
                  const float* __restrict__ query,
                  float* __restrict__ out)
{
    __shared__ unsigned short As[BMF][LPAD];
    __shared__ unsigned short Bs[BNF][LPAD];
    __shared__ float redA[4][BMF];
    __shared__ float redB[2][BNF];
    __shared__ float rpS[BMF];
    __shared__ float rqS[BNF];

    const int tid = threadIdx.x;
    const int m0  = blockIdx.x * BMF;
    const int q   = blockIdx.y;

    const int mA  = tid & (BMF - 1);
    const int krA = tid >> 7;
    const int wiA = m0 + mA;
    const bool va = (wiA < MROWS);
    const int wA  = va ? (wiA / IJ) : 0;
    const int iA  = va ? (wiA - wA * IJ) : 0;
    const float* pA = proto + wA * (CD * IJ) + iA;

    const bool tb  = (tid < 448);
    const int jB   = tb ? (tid % BNF) : 0;
    const int krB  = tb ? (tid / BNF) : 0;
    const bool vb  = tb && (jB < IJ);
    const float* qB = query + q * (CD * IJ) + jB;

    float ssA = 0.f, ssB = 0.f;

    const int wv   = tid >> 6;
    const int lane = tid & 63;
    const int wm0  = (wv >> 1) * 32;
    const int wn0  = (wv & 1) * 112;
    const int fr   = lane & 15;
    const int fq   = lane >> 4;

    f32x4 acc[2][7];
    #pragma unroll
    for (int a = 0; a < 2; a++)
        #pragma unroll
        for (int b = 0; b < 7; b++)
            acc[a][b] = (f32x4){0.f, 0.f, 0.f, 0.f};

    for (int it = 0; it < CD / 32; ++it) {
        const int c0 = it * 32;
        {
            float v[8];
            #pragma unroll
            for (int e = 0; e < 8; e++) {
                int c = c0 + krA * 8 + e;
                v[e] = va ? pA[c * IJ] : 0.f;
            }
            #pragma unroll
            for (int e = 0; e < 8; e++) ssA += v[e] * v[e];
            union { unsigned short s[8]; uint4 u; } pk;
            #pragma unroll
            for (int e = 0; e < 8; e++) pk.s[e] = f2bf(v[e]);
            *(uint4*)&As[mA][krA * 8] = pk.u;
        }
        if (tb) {
            #pragma unroll
            for (int h = 0; h < 2; ++h) {
                float v[8];
                #pragma unroll
                for (int e = 0; e < 8; e++) {
                    int c = c0 + krB * 16 + h * 8 + e;
                    v[e] = vb ? qB[c * IJ] : 0.f;
                }
                #pragma unroll
                for (int e = 0; e < 8; e++) ssB += v[e] * v[e];
                union { unsigned short s[8]; uint4 u; } pk;
                #pragma unroll
                for (int e = 0; e < 8; e++) pk.s[e] = f2bf(v[e]);
                *(uint4*)&Bs[jB][krB * 16 + h * 8] = pk.u;
            }
        }
        __syncthreads();
        bf16x8 af[2], bfv[7];
        #pragma unroll
        for (int tm = 0; tm < 2; tm++)
            af[tm] = *(const bf16x8*)&As[wm0 + tm * 16 + fr][fq * 8];
        #pragma unroll
        for (int tn = 0; tn < 7; tn++)
            bfv[tn] = *(const bf16x8*)&Bs[wn0 + tn * 16 + fr][fq * 8];
        #pragma unroll
        for (int tm = 0; tm < 2; tm++)
            #pragma unroll
            for (int tn = 0; tn < 7; tn++)
                acc[tm][tn] = __builtin_amdgcn_mfma_f32_16x16x32_bf16(
                    af[tm], bfv[tn], acc[tm][tn], 0, 0, 0);
        __syncthreads();
    }

    redA[krA][mA] = ssA;
    if (tb) redB[krB][jB] = ssB;
    __syncthreads();
    if (tid < BMF) {
        rpS[tid] = sqrtf(redA[0][tid] + redA[1][tid] + redA[2][tid] + redA[3][tid]);
    } else if (tid >= 256 && tid < 256 + BNF) {
        int j = tid - 256;
        rqS[j] = sqrtf(redB[0][j] + redB[1][j]);
    }
    __syncthreads();

    #pragma unroll
    for (int tm = 0; tm < 2; tm++) {
        #pragma unroll
        for (int tn = 0; tn < 7; tn++) {
            #pragma unroll
            for (int r = 0; r < 4; r++) {
                int rl = wm0 + tm * 16 + fq * 4 + r;
                int cl = wn0 + tn * 16 + fr;
                int wi = m0 + rl;
                if (wi < MROWS && cl < IJ) {
                    float denom = fmaxf(rpS[rl] * rqS[cl], 1e-8f);
                    out[(size_t)(q * MROWS + wi) * IJ + cl] = acc[tm][tn][r] / denom;
                }
            }
        }
    }
}

// ---------------------------------------------------------------------------
extern "C" void kernel_launch(void* const* d_in, const int* in_sizes, int n_in,
                              void* d_out, int out_size, void* d_ws, size_t ws_size,
                              hipStream_t stream) {
    const float* proto = (const float*)d_in[0];
    const float* query = (const float*)d_in[1];
    float* out = (float*)d_out;

    // workspace layout
    const size_t off_pT = 0;                       // 1960*640*2 = 2,508,800
    const size_t off_qT = 2508800;                 // 58800*640*2 = 75,264,000
    const size_t off_pn = 77772800;                // 1960*4
    const size_t off_qn = 77780736;                // 58800*4
    const size_t need   = 78015936;

    if (ws_size < need) {
        dim3 grid((MROWS + BMF - 1) / BMF, QN);
        sim_fallback<<<grid, 512, 0, stream>>>(proto, query, out);
        return;
    }

    char* ws = (char*)d_ws;
    uint4* pT = (uint4*)(ws + off_pT);
    uint4* qT = (uint4*)(ws + off_qT);
    float* pn = (float*)(ws + off_pn);
    float* qn = (float*)(ws + off_qn);

    prep_kernel<<<dim3(13, QN), 256, 0, stream>>>(query, qT, qn);
    prep_kernel<<<dim3(13, WN), 256, 0, stream>>>(proto, pT, pn);

    gemm_kernel<<<dim3(NWG), 512, 0, stream>>>(pT, qT, pn, qn, out);
}

// Round 8
// 351.997 us; speedup vs baseline: 1.4307x; 1.1164x over previous
//
#include <hip/hip_runtime.h>
#include <stdint.h>

#define QN    300
#define WN    10
#define CD    640
#define IJ    196
#define MROWS 1960              // WN*IJ
#define NTOT  58800             // QN*IJ
#define OUTQ  384160            // MROWS*IJ
#define EPSV  1e-8f

#define BM    256
#define BN    256
#define BK    64
#define BUFE  ((BM + BN) * BK)         // 32768 ushorts = 64 KB per buffer
#define NTK   (CD / BK)                // 10 K-tiles

#define MT_TILES 8                     // m tiles of 256 (pad 2048)
#define NT_TILES 230                   // n tiles of 256 (pad 58880)
#define NWG      (MT_TILES * NT_TILES) // 1840, divisible by 8
#define CPX      (NWG / 8)             // 230

typedef __attribute__((ext_vector_type(8))) short bf16x8;
typedef __attribute__((ext_vector_type(4))) float f32x4;

__device__ __forceinline__ unsigned short f2bf(float f) {
    uint32_t u = __float_as_uint(f);
    u += 0x7FFFu + ((u >> 16) & 1u);   // RNE
    return (unsigned short)(u >> 16);
}

__device__ __forceinline__ void gload16(const void* g, void* l) {
    __builtin_amdgcn_global_load_lds(
        (const __attribute__((address_space(1))) void*)g,
        (__attribute__((address_space(3))) void*)l,
        16, 0, 0);
}

// ---------------------------------------------------------------------------
// Pre-pass: X[B][640][196] fp32 -> XT[B*196][640] bf16 (k contiguous), with
// the 3-bit swizzle baked per 16B unit within each 8-unit (64-elem) K-group:
// stored_unit = (u&8) | ((u&7) ^ (row&7)).  Also fp32 norms.
// ---------------------------------------------------------------------------
__global__ __launch_bounds__(256)
void prep_kernel(const float* __restrict__ X, uint4* __restrict__ XT,
                 float* __restrict__ nrm)
{
    __shared__ float T[128][21];
    __shared__ float ssL[16][17];

    const int b  = blockIdx.y;
    const int i0 = blockIdx.x * 16;
    const int t  = threadIdx.x;
    const float* Xb = X + (size_t)b * (CD * IJ);

    const int cA  = t >> 2;              // 0..63
    const int i4  = (t & 3) * 4;         // 0,4,8,12
    const int iv  = i0 + i4;
    const bool liv = (iv <= IJ - 4);

    const int il = t >> 4;               // 0..15
    const int u  = t & 15;               // 0..15
    float ss = 0.f;

    const int ig   = i0 + il;
    const bool wok = (ig < IJ);
    const int rowg = b * IJ + (wok ? ig : IJ - 1);
    const int uxor = rowg & 7;

    for (int cc = 0; cc < CD / 128; ++cc) {
        #pragma unroll
        for (int pass = 0; pass < 2; ++pass) {
            int cl = pass * 64 + cA;
            int c  = cc * 128 + cl;
            float4 v = make_float4(0.f, 0.f, 0.f, 0.f);
            if (liv) v = *(const float4*)&Xb[(size_t)c * IJ + iv];
            T[cl][i4 + 0] = v.x; T[cl][i4 + 1] = v.y;
            T[cl][i4 + 2] = v.z; T[cl][i4 + 3] = v.w;
        }
        __syncthreads();
        float v[8];
        #pragma unroll
        for (int r = 0; r < 8; ++r) { v[r] = T[u * 8 + r][il]; ss += v[r] * v[r]; }
        if (wok) {
            union { unsigned short s[8]; uint4 q; } pk;
            #pragma unroll
            for (int r = 0; r < 8; ++r) pk.s[r] = f2bf(v[r]);
            int us = (u & 8) | ((u & 7) ^ uxor);
            XT[(size_t)rowg * (CD / 8) + cc * 16 + us] = pk.q;
        }
        __syncthreads();
    }

    ssL[il][u] = ss;
    __syncthreads();
    if (t < 16) {
        int igw = i0 + t;
        if (igw < IJ) {
            float s = 0.f;
            #pragma unroll
            for (int k = 0; k < 16; ++k) s += ssL[t][k];
            nrm[b * IJ + igw] = sqrtf(s);
        }
    }
}

// ---------------------------------------------------------------------------
// GEMM: C[m][n] = sum_c AT[m][c]*BT[n][c].  256x256 tile, BK=64, 8 waves
// (2M x 4N), per-wave 128x64 (acc[8][4] of 16x16x32).
//
// vs round 7 (same staging/vmcnt skeleton, which passed):
//  (1) SWAPPED MFMA OPERANDS: mfma(b_frag, a_frag).  Operands are symmetric
//      (row x K dots), so math is identical; D-layout becomes col=m (lane&15),
//      rows = 4 CONSECUTIVE n per lane -> epilogue stores float4 (32 x4-stores
//      per thread instead of 128 scalar stores).  196%4==0 and 58800%4==0 so
//      an aligned n-quad never crosses a q row and validity is quad-uniform.
//  (2) LEADING-ONLY BARRIERS on P1,P2,P3,P5,P6,P7 (trailing kept only at the
//      P4/P8 vmcnt gates).  Hazard audit: a stage in phase p targets a region
//      whose last ds_reads ran in phase <= p-1; any wave issuing that stage
//      has passed phase p's leading barrier, which every wave reaches only
//      after its own lgkmcnt(0) of phase p-1 => all prior reads of the target
//      region completed.  Gate phases keep VMC(2)+BAR so ALL waves' staging
//      (each wave stages rows that OTHER waves read) is landed before the
//      next tile's reads.  vmcnt never drains to 0 in the loop.
// ---------------------------------------------------------------------------
__global__ __launch_bounds__(512, 2)
void gemm_kernel(const uint4* __restrict__ AT, const uint4* __restrict__ BT,
                 const float* __restrict__ pn, const float* __restrict__ qn,
                 float* __restrict__ out)
{
    __shared__ unsigned short lds[2 * BUFE];   // 128 KB

    const int bid = blockIdx.x;
    const int swz = (bid & 7) * CPX + (bid >> 3);   // bijective (1840%8==0)
    const int mt  = swz & (MT_TILES - 1);
    const int nt  = swz >> 3;
    const int m0  = mt * BM;
    const int n0  = nt * BN;

    const int t  = threadIdx.x;
    const int w  = t >> 6, l = t & 63;
    const int fr = l & 15, fq = l >> 4;
    const int wm0 = (w >> 2) * 128;   // 2 M-waves
    const int wn0 = (w & 3) * 64;     // 4 N-waves

    // ---- staging pointers (each stream staged once per K-tile it serves)
    const int lr = l >> 3, lu = l & 7;
    int ra00 = m0 +   0 + w * 8 + lr; if (ra00 > MROWS - 1) ra00 = MROWS - 1;
    int ra01 = m0 +  64 + w * 8 + lr; if (ra01 > MROWS - 1) ra01 = MROWS - 1;
    int ra10 = m0 + 128 + w * 8 + lr; if (ra10 > MROWS - 1) ra10 = MROWS - 1;
    int ra11 = m0 + 192 + w * 8 + lr; if (ra11 > MROWS - 1) ra11 = MROWS - 1;
    int rb00 = n0 +   0 + w * 8 + lr; if (rb00 > NTOT - 1) rb00 = NTOT - 1;
    int rb01 = n0 +  64 + w * 8 + lr; if (rb01 > NTOT - 1) rb01 = NTOT - 1;
    int rb10 = n0 + 128 + w * 8 + lr; if (rb10 > NTOT - 1) rb10 = NTOT - 1;
    int rb11 = n0 + 192 + w * 8 + lr; if (rb11 > NTOT - 1) rb11 = NTOT - 1;
    const uint4* ga00 = AT + (size_t)ra00 * 80 + lu;
    const uint4* ga01 = AT + (size_t)ra01 * 80 + lu;
    const uint4* ga10 = AT + (size_t)ra10 * 80 + lu;
    const uint4* ga11 = AT + (size_t)ra11 * 80 + lu;
    const uint4* gb00 = BT + (size_t)rb00 * 80 + lu;
    const uint4* gb01 = BT + (size_t)rb01 * 80 + lu;
    const uint4* gb10 = BT + (size_t)rb10 * 80 + lu;
    const uint4* gb11 = BT + (size_t)rb11 * 80 + lu;
    // wave-uniform LDS element offsets (HW adds lane*16B)
    const int la00 = (  0 + w * 8) * 64;
    const int la01 = ( 64 + w * 8) * 64;
    const int la10 = (128 + w * 8) * 64;
    const int la11 = (192 + w * 8) * 64;
    const int lb00 = BM * 64 + (  0 + w * 8) * 64;
    const int lb01 = BM * 64 + ( 64 + w * 8) * 64;
    const int lb10 = BM * 64 + (128 + w * 8) * 64;
    const int lb11 = BM * 64 + (192 + w * 8) * 64;

    // ---- fragment read bases + swizzle keys (loop-invariant)
    const int fqS0 = fq << 3;
    const int fqS1 = (fq + 4) << 3;
    int baA[8], kyA[8], baB[4], kyB[4];
    #pragma unroll
    for (int i = 0; i < 8; ++i) {
        int rowa = wm0 + i * 16 + fr;
        baA[i] = rowa * 64;  kyA[i] = (rowa & 7) << 3;
    }
    #pragma unroll
    for (int i = 0; i < 4; ++i) {
        int rowb = wn0 + i * 16 + fr;
        baB[i] = BM * 64 + rowb * 64;  kyB[i] = (rowb & 7) << 3;
    }

    f32x4 acc[8][4];
    #pragma unroll
    for (int a = 0; a < 8; ++a)
        #pragma unroll
        for (int bb = 0; bb < 4; ++bb)
            acc[a][bb] = (f32x4){0.f, 0.f, 0.f, 0.f};

#define ST2(PA, PB, LA, LB)                                               \
    gload16(PA, (char*)&lds[(LA)]); PA += 8;                              \
    gload16(PB, (char*)&lds[(LB)]); PB += 8;

#define RD_A(OC, G)                                                       \
    _Pragma("unroll")                                                     \
    for (int mm = 0; mm < 4; ++mm) {                                      \
        af[mm]   = *(const bf16x8*)&lds[(OC) + baA[(G)+mm]                \
                                        + (fqS0 ^ kyA[(G)+mm])];          \
        af[4+mm] = *(const bf16x8*)&lds[(OC) + baA[(G)+mm]                \
                                        + (fqS1 ^ kyA[(G)+mm])];          \
    }
#define RD_B(BV, OC, G)                                                   \
    _Pragma("unroll")                                                     \
    for (int nn = 0; nn < 2; ++nn) {                                      \
        BV[nn]   = *(const bf16x8*)&lds[(OC) + baB[(G)+nn]                \
                                        + (fqS0 ^ kyB[(G)+nn])];          \
        BV[2+nn] = *(const bf16x8*)&lds[(OC) + baB[(G)+nn]                \
                                        + (fqS1 ^ kyB[(G)+nn])];          \
    }
// swapped operands: D col (lane&15) = m, D rows (fq*4+reg) = n
#define MF(MB, NB, BV)                                                    \
    _Pragma("unroll")                                                     \
    for (int ks = 0; ks < 2; ++ks)                                        \
        _Pragma("unroll")                                                 \
        for (int mm = 0; mm < 4; ++mm)                                    \
            _Pragma("unroll")                                             \
            for (int nn = 0; nn < 2; ++nn)                                \
                acc[(MB)+mm][(NB)+nn] =                                   \
                    __builtin_amdgcn_mfma_f32_16x16x32_bf16(              \
                        BV[ks*2+nn], af[ks*4+mm],                         \
                        acc[(MB)+mm][(NB)+nn], 0, 0, 0);

#define BAR    __builtin_amdgcn_s_barrier()
#define LGKM0  do { asm volatile("s_waitcnt lgkmcnt(0)" ::: "memory");    \
                    __builtin_amdgcn_sched_barrier(0); } while (0)
#define VMC(N) asm volatile("s_waitcnt vmcnt(" #N ")" ::: "memory")
#define PRIO1  __builtin_amdgcn_s_setprio(1)
#define PRIO0  __builtin_amdgcn_s_setprio(0)

    // ---- prologue: tile0 fully -> buf0; tile1's A0 -> buf1.  10 loads;
    // VMC(2) -> tile0's 8 landed, tile1-A0 (2) still in flight.
    ST2(ga00, ga01, la00, la01);               // t0 A0
    ST2(gb00, gb01, lb00, lb01);               // t0 B0
    ST2(ga10, ga11, la10, la11);               // t0 A1
    ST2(gb10, gb11, lb10, lb11);               // t0 B1
    ST2(ga00, ga01, BUFE + la00, BUFE + la01); // t1 A0
    VMC(2); BAR;

    for (int i5 = 0; i5 < NTK / 2; ++i5) {
        bf16x8 af[8], b0[4], b1[4];
        // ======== even tile (buf0); stages -> buf1 (dead) except P4
        // P1: rd A0-3 + B0-1; st B0(odd)->buf1
        RD_A(0, 0); RD_B(b0, 0, 0);
        ST2(gb00, gb01, BUFE + lb00, BUFE + lb01);
        BAR; LGKM0;
        PRIO1; MF(0, 0, b0); PRIO0;
        // P2: rd B2-3; st A1(odd)->buf1
        RD_B(b1, 0, 2);
        ST2(ga10, ga11, BUFE + la10, BUFE + la11);
        BAR; LGKM0;
        PRIO1; MF(0, 2, b1); PRIO0;
        // P3: rd A4-7; st B1(odd)->buf1
        RD_A(0, 4);
        ST2(gb10, gb11, BUFE + lb10, BUFE + lb11);
        BAR; LGKM0;
        PRIO1; MF(4, 2, b1); PRIO0;
        // P4: regs only; st A0(even+2)->buf0 (all buf0 reads done at P3);
        //     gate: odd tile fully landed across ALL waves, 2 in flight.
        ST2(ga00, ga01, la00, la01);
        PRIO1; MF(4, 0, b0); PRIO0;
        VMC(2); BAR;
        // ======== odd tile (buf1); stages -> buf0 (dead) except P8
        // P5: rd A0-3 + B0-1; st B0(even+2)->buf0
        RD_A(BUFE, 0); RD_B(b0, BUFE, 0);
        ST2(gb00, gb01, lb00, lb01);
        BAR; LGKM0;
        PRIO1; MF(0, 0, b0); PRIO0;
        // P6: rd B2-3; st A1(even+2)->buf0
        RD_B(b1, BUFE, 2);
        ST2(ga10, ga11, la10, la11);
        BAR; LGKM0;
        PRIO1; MF(0, 2, b1); PRIO0;
        // P7: rd A4-7; st B1(even+2)->buf0
        RD_A(BUFE, 4);
        ST2(gb10, gb11, lb10, lb11);
        BAR; LGKM0;
        PRIO1; MF(4, 2, b1); PRIO0;
        // P8: st A0(odd+2)->buf1; gate for tile even+2
        ST2(ga00, ga01, BUFE + la00, BUFE + la01);
        PRIO1; MF(4, 0, b0); PRIO0;
        VMC(2); BAR;
    }

    VMC(0);   // drain tail garbage loads before epilogue/endpgm

#undef ST2
#undef RD_A
#undef RD_B
#undef MF
#undef BAR
#undef LGKM0
#undef VMC
#undef PRIO1
#undef PRIO0

    // ---- epilogue (swapped D-layout): frag (tm,tn), lane (fq,fr):
    //   m = m0 + wm0 + tm*16 + fr          (D col)
    //   n = n0 + wn0 + tn*16 + fq*4 + e    (D rows, e=0..3: consecutive n)
    // n is a multiple of 4; 196%4==0 and 58800%4==0 => an aligned quad never
    // crosses a q row and validity is quad-uniform -> float4 stores.
    float4 rqv4[4];
    int    nok[4];
    size_t ob[4];
    #pragma unroll
    for (int tn = 0; tn < 4; ++tn) {
        int n = n0 + wn0 + tn * 16 + fq * 4;
        nok[tn] = (n < NTOT);
        int nc = nok[tn] ? n : NTOT - 4;
        int q  = nc / IJ;
        int j  = nc - q * IJ;
        rqv4[tn] = *(const float4*)&qn[nc];
        ob[tn] = (size_t)q * OUTQ + j;
    }
    #pragma unroll
    for (int tm = 0; tm < 8; ++tm) {
        int m = m0 + wm0 + tm * 16 + fr;
        if (m < MROWS) {
            float rp = pn[m];
            #pragma unroll
            for (int tn = 0; tn < 4; ++tn) {
                if (nok[tn]) {
                    f32x4 a = acc[tm][tn];
                    float4 o;
                    o.x = a[0] * __builtin_amdgcn_rcpf(fmaxf(rp * rqv4[tn].x, EPSV));
                    o.y = a[1] * __builtin_amdgcn_rcpf(fmaxf(rp * rqv4[tn].y, EPSV));
                    o.z = a[2] * __builtin_amdgcn_rcpf(fmaxf(rp * rqv4[tn].z, EPSV));
                    o.w = a[3] * __builtin_amdgcn_rcpf(fmaxf(rp * rqv4[tn].w, EPSV));
                    *(float4*)&out[ob[tn] + (size_t)m * IJ] = o;
                }
            }
        }
    }
}

// ---------------------------------------------------------------------------
// Fallback (round-1 kernel, known-passing) if ws_size is insufficient.
// ---------------------------------------------------------------------------
#define BMF 128
#define BNF 224
#define LPAD 40
__global__ __launch_bounds__(512, 4)
void sim_fallback(const float* __restrict__ proto,
                  const float* __restrict__ query,
                  float* __restrict__ out)
{
    __shared__ unsigned short As[BMF][LPAD];
    __shared__ unsigned short Bs[BNF][LPAD];
    __shared__ float redA[4][BMF];
    __shared__ float redB[2][BNF];
    __shared__ float rpS[BMF];
    __shared__ float rqS[BNF];

    const int tid = threadIdx.x;
    const int m0  = blockIdx.x * BMF;
    const int q   = blockIdx.y;

    const int mA  = tid & (BMF - 1);
    const int krA = tid >> 7;
    const int wiA = m0 + mA;
    const bool va = (wiA < MROWS);
    const int wA  = va ? (wiA / IJ) : 0;
    const int iA  = va ? (wiA - wA * IJ) : 0;
    const float* pA = proto + wA * (CD * IJ) + iA;

    const bool tb  = (tid < 448);
    const int jB   = tb ? (tid % BNF) : 0;
    const int krB  = tb ? (tid / BNF) : 0;
    const bool vb  = tb && (jB < IJ);
    const float* qB = query + q * (CD * IJ) + jB;

    float ssA = 0.f, ssB = 0.f;

    const int wv   = tid >> 6;
    const int lane = tid & 63;
    const int wm0  = (wv >> 1) * 32;
    const int wn0  = (wv & 1) * 112;
    const int fr   = lane & 15;
    const int fq   = lane >> 4;

    f32x4 acc[2][7];
    #pragma unroll
    for (int a = 0; a < 2; a++)
        #pragma unroll
        for (int b = 0; b < 7; b++)
            acc[a][b] = (f32x4){0.f, 0.f, 0.f, 0.f};

    for (int it = 0; it < CD / 32; ++it) {
        const int c0 = it * 32;
        {
            float v[8];
            #pragma unroll
            for (int e = 0; e < 8; e++) {
                int c = c0 + krA * 8 + e;
                v[e] = va ? pA[c * IJ] : 0.f;
            }
            #pragma unroll
            for (int e = 0; e < 8; e++) ssA += v[e] * v[e];
            union { unsigned short s[8]; uint4 u; } pk;
            #pragma unroll
            for (int e = 0; e < 8; e++) pk.s[e] = f2bf(v[e]);
            *(uint4*)&As[mA][krA * 8] = pk.u;
        }
        if (tb) {
            #pragma unroll
            for (int h = 0; h < 2; ++h) {
                float v[8];
                #pragma unroll
                for (int e = 0; e < 8; e++) {
                    int c = c0 + krB * 16 + h * 8 + e;
                    v[e] = vb ? qB[c * IJ] : 0.f;
                }
                #pragma unroll
                for (int e = 0; e < 8; e++) ssB += v[e] * v[e];
                union { unsigned short s[8]; uint4 u; } pk;
                #pragma unroll
                for (int e = 0; e < 8; e++) pk.s[e] = f2bf(v[e]);
                *(uint4*)&Bs[jB][krB * 16 + h * 8] = pk.u;
            }
        }
        __syncthreads();
        bf16x8 af[2], bfv[7];
        #pragma unroll
        for (int tm = 0; tm < 2; tm++)
            af[tm] = *(const bf16x8*)&As[wm0 + tm * 16 + fr][fq * 8];
        #pragma unroll
        for (int tn = 0; tn < 7; tn++)
            bfv[tn] = *(const bf16x8*)&Bs[wn0 + tn * 16 + fr][fq * 8];
        #pragma unroll
        for (int tm = 0; tm < 2; tm++)
            #pragma unroll
            for (int tn = 0; tn < 7; tn++)
                acc[tm][tn] = __builtin_amdgcn_mfma_f32_16x16x32_bf16(
                    af[tm], bfv[tn], acc[tm][tn], 0, 0, 0);
        __syncthreads();
    }

    redA[krA][mA] = ssA;
    if (tb) redB[krB][jB] = ssB;
    __syncthreads();
    if (tid < BMF) {
        rpS[tid] = sqrtf(redA[0][tid] + redA[1][tid] + redA[2][tid] + redA[3][tid]);
    } else if (tid >= 256 && tid < 256 + BNF) {
        int j = tid - 256;
        rqS[j] = sqrtf(redB[0][j] + redB[1][j]);
    }
    __syncthreads();

    #pragma unroll
    for (int tm = 0; tm < 2; tm++) {
        #pragma unroll
        for (int tn = 0; tn < 7; tn++) {
            #pragma unroll
            for (int r = 0; r < 4; r++) {
                int rl = wm0 + tm * 16 + fq * 4 + r;
                int cl = wn0 + tn * 16 + fr;
                int wi = m0 + rl;
                if (wi < MROWS && cl < IJ) {
                    float denom = fmaxf(rpS[rl] * rqS[cl], 1e-8f);
                    out[(size_t)(q * MROWS + wi) * IJ + cl] = acc[tm][tn][r] / denom;
                }
            }
        }
    }
}

// ---------------------------------------------------------------------------
extern "C" void kernel_launch(void* const* d_in, const int* in_sizes, int n_in,
                              void* d_out, int out_size, void* d_ws, size_t ws_size,
                              hipStream_t stream) {
    const float* proto = (const float*)d_in[0];
    const float* query = (const float*)d_in[1];
    float* out = (float*)d_out;

    // workspace layout
    const size_t off_pT = 0;                       // 1960*640*2 = 2,508,800
    const size_t off_qT = 2508800;                 // 58800*640*2 = 75,264,000
    const size_t off_pn = 77772800;                // 1960*4
    const size_t off_qn = 77780736;                // 58800*4
    const size_t need   = 78015936;

    if (ws_size < need) {
        dim3 grid((MROWS + BMF - 1) / BMF, QN);
        sim_fallback<<<grid, 512, 0, stream>>>(proto, query, out);
        return;
    }

    char* ws = (char*)d_ws;
    uint4* pT = (uint4*)(ws + off_pT);
    uint4* qT = (uint4*)(ws + off_qT);
    float* pn = (float*)(ws + off_pn);
    float* qn = (float*)(ws + off_qn);

    prep_kernel<<<dim3(13, QN), 256, 0, stream>>>(query, qT, qn);
    prep_kernel<<<dim3(13, WN), 256, 0, stream>>>(proto, pT, pn);

    gemm_kernel<<<dim3(NWG), 512, 0, stream>>>(pT, qT, pn, qn, out);
}